// Round 25
// baseline (433.924 us; speedup 1.0000x reference)
//
#include <hip/hip_runtime.h>
#include <math.h>

// ESMMimicryModule: B=8 S=2048 H=8 NL=128 DF=VF=64 NF=1280 HS=33 FEAT=1313
// Round 25: V-transpose moved producer-side. k_qve epilogue writes Ev in the
// pre-transposed+swizzled Vt-tile layout (EvT[z][tile][d*128+swz]); k_land's
// V staging becomes a coalesced f16x8 copy (was 8 scalar ds_writes/chunk, done
// 2x per tile). Bit-identical values & layout at the read side. Rest = R24.

namespace {

constexpr int B = 8, S = 2048, H = 8, NL = 128, DF = 64, VF = 64;
constexpr int NF = 1280, HS = 33, FEAT = 1313, FEATP = 1314;
constexpr int SEG = 16, HV = H * VF;            // 512
constexpr int KSF = 1344;                        // padded feature-K (21*64)
constexpr int NSPL = 4;                          // key chunks in split-S flash
constexpr long ROWS = (long)B * S;               // 16384
constexpr float INV_SCALE = 0.35355339059327373f;

typedef _Float16 f16;
typedef _Float16 f16x8 __attribute__((ext_vector_type(8)));
typedef _Float16 f16x4 __attribute__((ext_vector_type(4)));
typedef float f32x4 __attribute__((ext_vector_type(4)));

// ---------------------------------------------------------------- cl = softmax(latent)*mask
__global__ __launch_bounds__(256) void k_cl(
    const float* __restrict__ lat, const float* __restrict__ masks,
    float* __restrict__ cl)
{
  long row = (long)blockIdx.x * 4 + (threadIdx.x >> 6);
  int l = threadIdx.x & 63;
  float v = (l < HS) ? lat[row * HS + l] : -INFINITY;
  float m = v;
  #pragma unroll
  for (int o = 32; o; o >>= 1) m = fmaxf(m, __shfl_xor(m, o));
  float e = (l < HS) ? expf(v - m) : 0.f;
  float s = e;
  #pragma unroll
  for (int o = 32; o; o >>= 1) s += __shfl_xor(s, o);
  if (l < HS) cl[row * HS + l] = e / s * masks[row];
}

// ---------------------------------------------------------------- prep: origA arena + 6 weight arenas
// blocks 0..10751: cvta body ; 10752..12615: cvtw6 body
__global__ __launch_bounds__(256) void k_prep(
    const float* __restrict__ xemb, const float* __restrict__ cl,
    const float* __restrict__ qlin, const float* __restrict__ klin,
    const float* __restrict__ vlin, const float* __restrict__ plin,
    const float* __restrict__ cfeat, const float* __restrict__ ccls,
    f16* __restrict__ origA,
    f16* __restrict__ WQt, f16* __restrict__ WKt, f16* __restrict__ WVt,
    f16* __restrict__ WPt, f16* __restrict__ WCFt, f16* __restrict__ WCCt)
{
  long bid = blockIdx.x;
  int tid = threadIdx.x;
  if (bid < 10752) {
    long idx = bid * 256 + tid;        // chunk id (row, c)
    long row = idx / 168;
    int c = (int)(idx - row * 168);
    int t = c >> 3, cs = c & 7;        // SOURCE chunk
    int k0 = t * 64 + cs * 8;
    f16x8 v;
    if (t < 20) {
      float4 a = *(const float4*)&xemb[row * NF + k0];
      float4 b = *(const float4*)&xemb[row * NF + k0 + 4];
      v[0] = (f16)a.x; v[1] = (f16)a.y; v[2] = (f16)a.z; v[3] = (f16)a.w;
      v[4] = (f16)b.x; v[5] = (f16)b.y; v[6] = (f16)b.z; v[7] = (f16)b.w;
    } else {
      #pragma unroll
      for (int i = 0; i < 8; ++i) {
        int k = k0 + i;
        float f = 0.f;
        if (k < NF) f = xemb[row * NF + k];
        else if (k < FEAT) f = cl[row * HS + (k - NF)];
        v[i] = (f16)f;
      }
    }
    int cd = cs ^ ((int)row & 7);
    *(f16x8*)&origA[row * KSF + t * 64 + cd * 8] = v;
  } else {
    constexpr long s1 = 172032, s2 = 193536, s3 = 365568, s4 = 387072,
                   s5 = 473088, s6 = 477184;
    long idx = (bid - 10752) * 256 + tid;
    if (idx >= s6) return;
    const float* src; f16* dst; int K, N, Npad, KS; long srcZ, rel;
    if (idx < s1)      { src = qlin;  dst = WQt;  K = FEAT; N = 64;  Npad = 64;  KS = KSF; srcZ = (long)FEATP * 64; rel = idx; }
    else if (idx < s2) { src = klin;  dst = WKt;  K = FEAT; N = 64;  Npad = 64;  KS = KSF; srcZ = (long)FEATP * 64; rel = idx - s1; }
    else if (idx < s3) { src = vlin;  dst = WVt;  K = FEAT; N = 64;  Npad = 64;  KS = KSF; srcZ = (long)FEATP * 64; rel = idx - s2; }
    else if (idx < s4) { src = plin;  dst = WPt;  K = FEAT; N = 64;  Npad = 64;  KS = KSF; srcZ = (long)FEATP * 64; rel = idx - s3; }
    else if (idx < s5) { src = cfeat; dst = WCFt; K = 512;  N = FEAT; Npad = KSF; KS = 512; srcZ = 0; rel = idx - s4; }
    else               { src = ccls;  dst = WCCt; K = 512;  N = HS;  Npad = 64;  KS = 512; srcZ = 0; rel = idx - s5; }
    long cpz = (long)Npad * (KS >> 3);
    long z = rel / cpz;
    long rem = rel - z * cpz;
    int n = (int)(rem / (KS >> 3));
    int c = (int)(rem - (long)n * (KS >> 3));
    int t = c >> 3, cs = c & 7;
    int cd = cs ^ (n & 7);
    int k0 = t * 64 + cd * 8;
    const float* sp = src + z * srcZ;
    f16x8 v;
    #pragma unroll
    for (int i = 0; i < 8; ++i) {
      int k = k0 + i;
      v[i] = (f16)((k < K && n < N) ? sp[(long)k * N + n] : 0.f);
    }
    *(f16x8*)&dst[rel * 8] = v;
  }
}

// ---------------------------------------------------------------- fp16 MFMA GEMM (generic)
// mode 1: fp16 swizzled arena (KSF stride, zero-fill col>=NR), LDS-staged
// mode 2: fp32 out * mask, col<NR
__global__ __launch_bounds__(256, 2) void k_mgemm(
    const f16* __restrict__ A, long aZOff, int aDiv,
    const f16* __restrict__ Wt, long wZOff, int wMod,
    int KT, int mode,
    float* __restrict__ C, long cZOff, int ldC,
    const float* __restrict__ biasBase, long biasZOff, float scale,
    f16* __restrict__ outA, int NR, const float* __restrict__ mask)
{
  const long KS = (long)KT * 64;
  int z = blockIdx.z;
  const f16* Ap = A + (long)(z / aDiv) * aZOff;
  const f16* Wp = Wt + (long)(z % wMod) * wZOff;
  long m0 = (long)blockIdx.x * 256;
  int n0 = blockIdx.y * 64;
  constexpr int BOFF = 256 * 64;
  __shared__ f16 lds[2][(256 + 64) * 64];
  int tid = threadIdx.x;
  int wv = tid >> 6, l = tid & 63;

  const f16* aW = Ap + (m0 + wv * 64 + (l >> 3)) * KS + (l & 7) * 8;
  const f16* bW = Wp + ((long)(n0 + wv * 16 + (l >> 3))) * KS + (l & 7) * 8;

  f32x4 acc[4][4];
  #pragma unroll
  for (int i = 0; i < 4; ++i)
    #pragma unroll
    for (int j = 0; j < 4; ++j) acc[i][j] = (f32x4){0.f, 0.f, 0.f, 0.f};

  auto stage = [&](int buf, int t) {
    f16* la = &lds[buf][(wv * 64) * 64];
    const f16* ga = aW + (long)t * 64;
    #pragma unroll
    for (int j = 0; j < 8; ++j)
      __builtin_amdgcn_global_load_lds(
          (const __attribute__((address_space(1))) void*)(ga + (long)j * 8 * KS),
          (__attribute__((address_space(3))) void*)(la + j * 8 * 64), 16, 0, 0);
    f16* lb = &lds[buf][BOFF + (wv * 16) * 64];
    const f16* gb = bW + (long)t * 64;
    #pragma unroll
    for (int j = 0; j < 2; ++j)
      __builtin_amdgcn_global_load_lds(
          (const __attribute__((address_space(1))) void*)(gb + (long)j * 8 * KS),
          (__attribute__((address_space(3))) void*)(lb + j * 8 * 64), 16, 0, 0);
  };

  stage(0, 0);
  int rA = (wv * 64 + (l & 15)) * 64;
  int rB = BOFF + (l & 15) * 64;
  int lc = l >> 4, lx = l & 7;
  for (int t = 0; t < KT; ++t) {
    int nb = t & 1;
    if (t + 1 < KT) {
      stage(nb ^ 1, t + 1);
      asm volatile("s_waitcnt vmcnt(10)" ::: "memory");
    } else {
      asm volatile("s_waitcnt vmcnt(0)" ::: "memory");
    }
    __syncthreads();
    const f16* base = &lds[nb][0];
    f16x8 af[4][2], bf[4][2];
    #pragma unroll
    for (int mi = 0; mi < 4; ++mi)
      #pragma unroll
      for (int kh = 0; kh < 2; ++kh)
        af[mi][kh] = *(const f16x8*)&base[rA + mi * 16 * 64 + (((kh * 4 + lc) ^ lx) << 3)];
    #pragma unroll
    for (int ni = 0; ni < 4; ++ni)
      #pragma unroll
      for (int kh = 0; kh < 2; ++kh)
        bf[ni][kh] = *(const f16x8*)&base[rB + ni * 16 * 64 + (((kh * 4 + lc) ^ lx) << 3)];
    #pragma unroll
    for (int mi = 0; mi < 4; ++mi)
      #pragma unroll
      for (int ni = 0; ni < 4; ++ni) {
        acc[mi][ni] = __builtin_amdgcn_mfma_f32_16x16x32_f16(af[mi][0], bf[ni][0], acc[mi][ni], 0, 0, 0);
        acc[mi][ni] = __builtin_amdgcn_mfma_f32_16x16x32_f16(af[mi][1], bf[ni][1], acc[mi][ni], 0, 0, 0);
      }
    __syncthreads();
  }

  int lr = (l >> 4) * 4;
  int lcn = l & 15;
  if (mode == 2) {
    #pragma unroll
    for (int mi = 0; mi < 4; ++mi) {
      #pragma unroll
      for (int r = 0; r < 4; ++r) {
        long row = m0 + wv * 64 + mi * 16 + lr + r;
        float mv = mask[row];
        #pragma unroll
        for (int ni = 0; ni < 4; ++ni) {
          int col = n0 + ni * 16 + lcn;
          if (col < NR) C[row * (long)ldC + col] = acc[mi][ni][r] * mv;
        }
      }
    }
  } else {  // mode 1
    f16* st = &lds[0][0];
    #pragma unroll
    for (int ni = 0; ni < 4; ++ni) {
      int coll = ni * 16 + lcn;
      int col = n0 + coll;
      bool ok = col < NR;
      #pragma unroll
      for (int mi = 0; mi < 4; ++mi) {
        int rowl = wv * 64 + mi * 16 + lr;
        #pragma unroll
        for (int r = 0; r < 4; ++r) {
          float v = ok ? acc[mi][ni][r] * scale : 0.f;
          st[(rowl + r) * 64 + coll] = (f16)v;
        }
      }
    }
    __syncthreads();
    int tt = n0 >> 6;
    for (int c = tid; c < 2048; c += 256) {
      int row = c >> 3, cd = c & 7;
      long grow = m0 + row;
      int r7 = (int)grow & 7;
      f16x8 v = *(const f16x8*)&st[row * 64 + cd * 8];
      *(f16x8*)&outA[grow * KSF + tt * 64 + ((cd ^ r7) << 3)] = v;
    }
  }
}

// ---------------------------------------------------------------- merged Eq+Ev | Ek+proj launch
// Single-buffered (m97 structure): 32KB LDS -> 4-5 blocks/CU.
// Ev written in pre-transposed+swizzled Vt-tile layout (EvT).
__global__ __launch_bounds__(256, 2) void k_qve(
    const f16* __restrict__ Aact, const f16* __restrict__ Aorig,
    const f16* __restrict__ WQl, const f16* __restrict__ WVl,
    const f16* __restrict__ wk, const f16* __restrict__ wp,
    const float* __restrict__ bqBase, const float* __restrict__ bvBase,
    const float* __restrict__ bk, const float* __restrict__ bp,
    f16* __restrict__ Eq16, f16* __restrict__ Ev16, f16* __restrict__ Ek16,
    float* __restrict__ projb,
    f16* __restrict__ qland16, f16* __restrict__ kland16)
{
  constexpr int KT = 21;
  __shared__ __align__(16) f16 shbuf[256 * 64];   // 32 KB single buffer
  int bid = blockIdx.x;
  int tid = threadIdx.x;
  int wv = tid >> 6, l = tid & 63;
  int l15 = l & 15, lc = l >> 4, lx = l & 7;
  int lr = (l >> 4) * 4;
  int lcn = l & 15;

  if (bid < 1024) {
    // ================= Eq+Ev body =================
    constexpr int BOFF = 128 * 64;
    int z = bid >> 4;                 // b*H + h
    int h = z & 7;
    const f16* Ap = Aact + (long)(z >> 3) * S * KSF;
    const f16* wqp = WQl + (long)h * 64 * KSF;
    const f16* wvp = WVl + (long)h * 64 * KSF;
    const float* bq = bqBase + (long)h * FEATP * 64;
    const float* bv = bvBase + (long)h * FEATP * 64;
    long m0 = (long)(bid & 15) * 128;

    const f16* aW = Ap + (m0 + wv * 32 + (l >> 3)) * KSF + (l & 7) * 8;

    f32x4 acc[2][8];
    #pragma unroll
    for (int i = 0; i < 2; ++i)
      #pragma unroll
      for (int j = 0; j < 8; ++j) acc[i][j] = (f32x4){0.f, 0.f, 0.f, 0.f};

    auto stage = [&](int t) {
      f16* la = &shbuf[(wv * 32) * 64];
      const f16* ga = aW + (long)t * 64;
      #pragma unroll
      for (int j = 0; j < 4; ++j)
        __builtin_amdgcn_global_load_lds(
            (const __attribute__((address_space(1))) void*)(ga + (long)j * 8 * KSF),
            (__attribute__((address_space(3))) void*)(la + j * 512), 16, 0, 0);
      f16* lb = &shbuf[BOFF + (wv * 32) * 64];
      #pragma unroll
      for (int j = 0; j < 4; ++j) {
        int brow = wv * 32 + j * 8 + (l >> 3);
        const f16* src = (brow < 64 ? wqp + (long)brow * KSF
                                    : wvp + (long)(brow - 64) * KSF)
                         + (l & 7) * 8 + (long)t * 64;
        __builtin_amdgcn_global_load_lds(
            (const __attribute__((address_space(1))) void*)src,
            (__attribute__((address_space(3))) void*)(lb + j * 512), 16, 0, 0);
      }
    };

    for (int t = 0; t < KT; ++t) {
      stage(t);
      asm volatile("s_waitcnt vmcnt(0)" ::: "memory");
      __syncthreads();
      const f16* base = &shbuf[0];
      f16x8 af[2][2], bf[8][2];
      #pragma unroll
      for (int mi = 0; mi < 2; ++mi)
        #pragma unroll
        for (int kh = 0; kh < 2; ++kh)
          af[mi][kh] = *(const f16x8*)&base[(wv * 32 + mi * 16 + l15) * 64 + (((kh * 4 + lc) ^ lx) << 3)];
      #pragma unroll
      for (int ni = 0; ni < 8; ++ni) {
        int n = ni * 16 + l15;
        #pragma unroll
        for (int kh = 0; kh < 2; ++kh)
          bf[ni][kh] = *(const f16x8*)&base[BOFF + n * 64 + (((kh * 4 + lc) ^ (n & 7)) << 3)];
      }
      #pragma unroll
      for (int mi = 0; mi < 2; ++mi)
        #pragma unroll
        for (int ni = 0; ni < 8; ++ni) {
          acc[mi][ni] = __builtin_amdgcn_mfma_f32_16x16x32_f16(af[mi][0], bf[ni][0], acc[mi][ni], 0, 0, 0);
          acc[mi][ni] = __builtin_amdgcn_mfma_f32_16x16x32_f16(af[mi][1], bf[ni][1], acc[mi][ni], 0, 0, 0);
        }
      __syncthreads();
    }

    f16* st = &shbuf[0];
    #pragma unroll
    for (int ni = 0; ni < 8; ++ni) {
      int col = ni * 16 + l15;
      float bvv = (col < 64) ? bq[col] : bv[col - 64];
      float scl = (col < 64) ? INV_SCALE : 1.f;
      #pragma unroll
      for (int mi = 0; mi < 2; ++mi) {
        int rowl = wv * 32 + mi * 16 + lr;
        #pragma unroll
        for (int r = 0; r < 4; ++r)
          st[(rowl + r) * 128 + col] = (f16)((acc[mi][ni][r] + bvv) * scl);
      }
    }
    __syncthreads();
    f16* oq = Eq16 + (long)z * S * 64;
    for (int c = tid; c < 1024; c += 256) {
      int rw = c >> 3, cc = c & 7;
      *(f16x8*)&oq[(m0 + rw) * 64 + cc * 8] = *(const f16x8*)&st[rw * 128 + cc * 8];
    }
    // EvT: pre-transposed+swizzled Vt tile. flat[d*128 + j*8 + ki] = V[(j^(d&7))*8+ki][d]
    f16* ovt = Ev16 + ((long)z * 16 + (int)(m0 >> 7)) * 8192;
    for (int c = tid; c < 1024; c += 256) {
      int d = c >> 4, j = c & 15;
      int k0 = (j ^ (d & 7)) * 8;
      f16x8 sv;
      #pragma unroll
      for (int ki = 0; ki < 8; ++ki)
        sv[ki] = st[(k0 + ki) * 128 + 64 + d];
      *(f16x8*)&ovt[d * 128 + j * 8] = sv;
    }
    for (int c = tid; c < 512; c += 256) {
      int lm = c >> 6, d = c & 63;
      float s = 0.f;
      #pragma unroll
      for (int i = 0; i < SEG; ++i) s += (float)st[(lm * SEG + i) * 128 + d];
      float v = s * (1.f / SEG);
      long li = (long)z * NL + (m0 >> 4) + lm;
      qland16[li * 64 + d] = (f16)v;
    }
  } else {
    // ================= Ek / proj body (BM=128) =================
    constexpr int BOFF = 128 * 64;
    int rel = bid - 1024;
    int zz2 = rel >> 4;
    int prob = zz2 >> 3, b = zz2 & 7;
    const f16* Ap = (prob ? Aorig : Aact) + (long)b * S * KSF;
    const f16* Wp = prob ? wp : wk;
    long m0 = (long)(rel & 15) * 128;

    const f16* aW = Ap + (m0 + wv * 32 + (l >> 3)) * KSF + (l & 7) * 8;
    const f16* bW = Wp + ((long)(wv * 16 + (l >> 3))) * KSF + (l & 7) * 8;

    f32x4 acc[2][4];
    #pragma unroll
    for (int i = 0; i < 2; ++i)
      #pragma unroll
      for (int j = 0; j < 4; ++j) acc[i][j] = (f32x4){0.f, 0.f, 0.f, 0.f};

    auto stage = [&](int t) {
      f16* la = &shbuf[(wv * 32) * 64];
      const f16* ga = aW + (long)t * 64;
      #pragma unroll
      for (int j = 0; j < 4; ++j)
        __builtin_amdgcn_global_load_lds(
            (const __attribute__((address_space(1))) void*)(ga + (long)j * 8 * KSF),
            (__attribute__((address_space(3))) void*)(la + j * 512), 16, 0, 0);
      f16* lb = &shbuf[BOFF + (wv * 16) * 64];
      const f16* gb = bW + (long)t * 64;
      #pragma unroll
      for (int j = 0; j < 2; ++j)
        __builtin_amdgcn_global_load_lds(
            (const __attribute__((address_space(1))) void*)(gb + (long)j * 8 * KSF),
            (__attribute__((address_space(3))) void*)(lb + j * 512), 16, 0, 0);
    };

    for (int t = 0; t < KT; ++t) {
      stage(t);
      asm volatile("s_waitcnt vmcnt(0)" ::: "memory");
      __syncthreads();
      const f16* base = &shbuf[0];
      f16x8 af[2][2], bf[4][2];
      #pragma unroll
      for (int mi = 0; mi < 2; ++mi)
        #pragma unroll
        for (int kh = 0; kh < 2; ++kh)
          af[mi][kh] = *(const f16x8*)&base[(wv * 32 + mi * 16 + l15) * 64 + (((kh * 4 + lc) ^ lx) << 3)];
      #pragma unroll
      for (int ni = 0; ni < 4; ++ni)
        #pragma unroll
        for (int kh = 0; kh < 2; ++kh)
          bf[ni][kh] = *(const f16x8*)&base[BOFF + (ni * 16 + l15) * 64 + (((kh * 4 + lc) ^ lx) << 3)];
      #pragma unroll
      for (int mi = 0; mi < 2; ++mi)
        #pragma unroll
        for (int ni = 0; ni < 4; ++ni) {
          acc[mi][ni] = __builtin_amdgcn_mfma_f32_16x16x32_f16(af[mi][0], bf[ni][0], acc[mi][ni], 0, 0, 0);
          acc[mi][ni] = __builtin_amdgcn_mfma_f32_16x16x32_f16(af[mi][1], bf[ni][1], acc[mi][ni], 0, 0, 0);
        }
      __syncthreads();
    }

    if (prob == 0) {
      f16* st = &shbuf[0];
      #pragma unroll
      for (int ni = 0; ni < 4; ++ni) {
        int col = ni * 16 + lcn;
        float bv = bk[col];
        #pragma unroll
        for (int mi = 0; mi < 2; ++mi) {
          int rowl = wv * 32 + mi * 16 + lr;
          #pragma unroll
          for (int r = 0; r < 4; ++r)
            st[(rowl + r) * 64 + col] = (f16)((acc[mi][ni][r] + bv) * INV_SCALE);
        }
      }
      __syncthreads();
      f16* o16 = Ek16 + (long)b * S * 64;
      for (int c = tid; c < 1024; c += 256) {
        int row = c >> 3, cc = c & 7;
        f16x8 v = *(const f16x8*)&st[row * 64 + cc * 8];
        *(f16x8*)&o16[(m0 + row) * 64 + cc * 8] = v;
      }
      for (int c = tid; c < 512; c += 256) {
        int lm = c >> 6, d = c & 63;
        float s = 0.f;
        #pragma unroll
        for (int i = 0; i < SEG; ++i) s += (float)st[(lm * SEG + i) * 64 + d];
        float v = s * (1.f / SEG);
        long li = (long)b * NL + (m0 >> 4) + lm;
        kland16[li * 64 + d] = (f16)v;
      }
    } else {
      float* Cp = projb + (long)b * S * 64;
      #pragma unroll
      for (int ni = 0; ni < 4; ++ni) {
        int col = ni * 16 + lcn;
        float bv = bp[col];
        #pragma unroll
        for (int mi = 0; mi < 2; ++mi) {
          long row = m0 + wv * 32 + mi * 16 + lr;
          #pragma unroll
          for (int r = 0; r < 4; ++r)
            Cp[(row + r) * 64 + col] = (acc[mi][ni][r] + bv) * 0.5f;
        }
      }
    }
  }
}

// ---------------------------------------------------------------- merged kernel_3 | kernel_2
// blocks 0..511: flash (Q frags in regs, K staged, V coalesced copy from EvT;
// 49.7KB -> 3 blocks/CU). blocks 512..575: kernel2 MFMA.
__global__ __launch_bounds__(256, 3) void k_land(
    const f16* __restrict__ qland16, const f16* __restrict__ kland16,
    const f16* __restrict__ Ek16, const f16* __restrict__ Ev16,
    const float* __restrict__ aggL, const float* __restrict__ masks,
    float* __restrict__ partU, float* __restrict__ partML,
    f16* __restrict__ k2h, float* __restrict__ colmax)
{
  __shared__ __align__(16) unsigned char smem[49664];
  int bid = blockIdx.x;
  int tid = threadIdx.x;
  int w = tid >> 6, l = tid & 63;
  int l15 = l & 15, lg4 = l >> 4, l7 = l & 7;

  if (bid < 512) {
    // ================= kernel3 body =================
    f16* Ks = (f16*)smem;                    // 128*64 = 16 KB
    f16* Vt = (f16*)(smem + 16384);          // 64*128 = 16 KB
    f16* Pb = (f16*)(smem + 32768);          // 4*16*128 = 16 KB
    float* Ms = (float*)(smem + 49152);      // 128 floats
    int chunk = bid & (NSPL - 1);
    int z2 = bid >> 2;
    int z = z2 >> 1, half = z2 & 1;
    int b = z >> 3, h = z & 7;
    int q0 = half * 64;
    float sigma = fabsf(aggL[h]) + 0.001f;
    float cpos = -sigma * (1.f / 16.f);

    // loop-invariant Q fragments straight from global (R21-proven safe)
    f16x8 af[2];
    #pragma unroll
    for (int kh = 0; kh < 2; ++kh)
      af[kh] = *(const f16x8*)&qland16[((long)z * NL + q0 + w * 16 + l15) * 64 + kh * 32 + lg4 * 8];

    f16* Pw = &Pb[w * 16 * 128];
    f32x4 Oa[4];
    #pragma unroll
    for (int i = 0; i < 4; ++i) Oa[i] = (f32x4){0.f, 0.f, 0.f, 0.f};
    float mrun[4] = {-INFINITY, -INFINITY, -INFINITY, -INFINITY};
    float lrun[4] = {0.f, 0.f, 0.f, 0.f};

    int t0beg = chunk * (S / 128 / NSPL), t0end = t0beg + S / 128 / NSPL;
    for (int t0 = t0beg; t0 < t0end; ++t0) {
      __syncthreads();
      for (int c = tid; c < 1024; c += 256) {
        int k = c >> 3, kc = c & 7;
        f16x8 v = *(const f16x8*)&Ek16[((long)b * S + t0 * 128 + k) * 64 + kc * 8];
        *(f16x8*)&Ks[k * 64 + ((kc ^ (k & 7)) << 3)] = v;
      }
      {
        const f16* evt = &Ev16[((long)z * 16 + t0) * 8192];
        for (int c = tid; c < 1024; c += 256)
          *(f16x8*)&Vt[c * 8] = *(const f16x8*)&evt[c * 8];
      }
      if (tid < 128)
        Ms[tid] = (masks[(long)b * S + t0 * 128 + tid] == 0.f) ? -1e6f : 0.f;
      __syncthreads();

      f32x4 sc[8];
      #pragma unroll
      for (int ct = 0; ct < 8; ++ct) {
        int n = ct * 16 + l15;
        f16x8 b0 = *(const f16x8*)&Ks[n * 64 + (((lg4) ^ (n & 7)) << 3)];
        f16x8 b1 = *(const f16x8*)&Ks[n * 64 + (((4 + lg4) ^ (n & 7)) << 3)];
        f32x4 zz = (f32x4){0.f, 0.f, 0.f, 0.f};
        zz = __builtin_amdgcn_mfma_f32_16x16x32_f16(af[0], b0, zz, 0, 0, 0);
        sc[ct] = __builtin_amdgcn_mfma_f32_16x16x32_f16(af[1], b1, zz, 0, 0, 0);
      }
      float tmax[4] = {-INFINITY, -INFINITY, -INFINITY, -INFINITY};
      #pragma unroll
      for (int ct = 0; ct < 8; ++ct) {
        float mk = Ms[ct * 16 + l15];
        int key = t0 * 128 + ct * 16 + l15;
        #pragma unroll
        for (int r = 0; r < 4; ++r) {
          int qg = q0 + w * 16 + lg4 * 4 + r;
          float a = (float)(key - 16 * qg);
          float ac = fminf(fmaxf(a, 0.f), 15.f);
          float dd = fabsf(a - ac);
          float sum = ac * ac - 15.f * ac + 120.f + 16.f * dd;
          float s = sc[ct][r] + cpos * sum + mk;
          sc[ct][r] = s;
          tmax[r] = fmaxf(tmax[r], s);
        }
      }
      #pragma unroll
      for (int r = 0; r < 4; ++r) {
        #pragma unroll
        for (int o = 1; o < 16; o <<= 1)
          tmax[r] = fmaxf(tmax[r], __shfl_xor(tmax[r], o));
      }
      float fr[4], lsum[4];
      #pragma unroll
      for (int r = 0; r < 4; ++r) {
        float mnew = fmaxf(mrun[r], tmax[r]);
        fr[r] = expf(mrun[r] - mnew);
        mrun[r] = mnew;
        lsum[r] = 0.f;
      }
      #pragma unroll
      for (int ct = 0; ct < 8; ++ct) {
        #pragma unroll
        for (int r = 0; r < 4; ++r) {
          float p = expf(sc[ct][r] - mrun[r]);
          sc[ct][r] = p;
          lsum[r] += p;
        }
      }
      #pragma unroll
      for (int r = 0; r < 4; ++r) {
        #pragma unroll
        for (int o = 1; o < 16; o <<= 1)
          lsum[r] += __shfl_xor(lsum[r], o);
        lrun[r] = lrun[r] * fr[r] + lsum[r];
      }
      f32x4 fv = (f32x4){fr[0], fr[1], fr[2], fr[3]};
      #pragma unroll
      for (int dt = 0; dt < 4; ++dt) Oa[dt] *= fv;
      #pragma unroll
      for (int ct = 0; ct < 8; ++ct) {
        int kc = ct * 2 + (l15 >> 3);
        int ki = l15 & 7;
        #pragma unroll
        for (int r = 0; r < 4; ++r) {
          int row = lg4 * 4 + r;
          Pw[row * 128 + ((kc ^ (row & 7)) << 3) + ki] = (f16)sc[ct][r];
        }
      }
      #pragma unroll
      for (int ks = 0; ks < 4; ++ks) {
        f16x8 pa = *(const f16x8*)&Pw[l15 * 128 + (((ks * 4 + lg4) ^ l7) << 3)];
        #pragma unroll
        for (int dt = 0; dt < 4; ++dt) {
          int n = dt * 16 + l15;
          f16x8 bv = *(const f16x8*)&Vt[n * 128 + (((ks * 4 + lg4) ^ (n & 7)) << 3)];
          Oa[dt] = __builtin_amdgcn_mfma_f32_16x16x32_f16(pa, bv, Oa[dt], 0, 0, 0);
        }
      }
    }
    #pragma unroll
    for (int r = 0; r < 4; ++r) {
      long qg = q0 + w * 16 + lg4 * 4 + r;
      long base = ((long)z * NL + qg) * NSPL + chunk;
      #pragma unroll
      for (int dt = 0; dt < 4; ++dt)
        partU[base * 64 + dt * 16 + l15] = Oa[dt][r];
      if (l15 == 0) {
        partML[base * 2] = mrun[r];
        partML[base * 2 + 1] = lrun[r];
      }
    }
  } else {
    // ================= kernel2 body (MFMA) =================
    f16* Qs2 = (f16*)smem;                   // 128*64
    f16* Ks2 = (f16*)(smem + 16384);         // 128*64
    float* colpart = (float*)(smem + 32768); // 516 floats
    int z = bid - 512;
    int b2 = z >> 3, h2 = z & 7;
    float sigma = fabsf(aggL[h2]) + 0.001f;
    for (int c = tid; c < 1024; c += 256) {
      int q = c >> 3, kc = c & 7;
      f16x8 v = *(const f16x8*)&qland16[((long)z * NL + q) * 64 + kc * 8];
      *(f16x8*)&Qs2[q * 64 + ((kc ^ (q & 7)) << 3)] = v;
      f16x8 u = *(const f16x8*)&kland16[((long)b2 * NL + q) * 64 + kc * 8];
      *(f16x8*)&Ks2[q * 64 + ((kc ^ (q & 7)) << 3)] = u;
    }
    __syncthreads();
    f32x4 acc[2][8];
    #pragma unroll
    for (int i = 0; i < 2; ++i)
      #pragma unroll
      for (int j = 0; j < 8; ++j) acc[i][j] = (f32x4){0.f, 0.f, 0.f, 0.f};
    f16x8 af[2][2];
    #pragma unroll
    for (int mi = 0; mi < 2; ++mi)
      #pragma unroll
      for (int kh = 0; kh < 2; ++kh)
        af[mi][kh] = *(const f16x8*)&Qs2[(w * 32 + mi * 16 + l15) * 64 + (((kh * 4 + lg4) ^ l7) << 3)];
    #pragma unroll
    for (int ni = 0; ni < 8; ++ni) {
      int n = ni * 16 + l15;
      f16x8 b0 = *(const f16x8*)&Ks2[n * 64 + ((lg4 ^ (n & 7)) << 3)];
      f16x8 b1 = *(const f16x8*)&Ks2[n * 64 + (((4 + lg4) ^ (n & 7)) << 3)];
      #pragma unroll
      for (int mi = 0; mi < 2; ++mi) {
        acc[mi][ni] = __builtin_amdgcn_mfma_f32_16x16x32_f16(af[mi][0], b0, acc[mi][ni], 0, 0, 0);
        acc[mi][ni] = __builtin_amdgcn_mfma_f32_16x16x32_f16(af[mi][1], b1, acc[mi][ni], 0, 0, 0);
      }
    }
    // pos term + row softmax + k2h store + col partials
    float colp[8];
    #pragma unroll
    for (int ni = 0; ni < 8; ++ni) colp[ni] = 0.f;
    f16* o2 = k2h + (long)z * NL * NL;
    #pragma unroll
    for (int mi = 0; mi < 2; ++mi) {
      float tmax[4] = {-INFINITY, -INFINITY, -INFINITY, -INFINITY};
      #pragma unroll
      for (int ni = 0; ni < 8; ++ni) {
        int m = ni * 16 + l15;
        #pragma unroll
        for (int r = 0; r < 4; ++r) {
          int row = w * 32 + mi * 16 + lg4 * 4 + r;
          float dd = fabsf((float)(row - m));
          float s = acc[mi][ni][r] - sigma * ((row == m) ? 5.3125f : 16.f * dd);
          acc[mi][ni][r] = s;
          tmax[r] = fmaxf(tmax[r], s);
        }
      }
      #pragma unroll
      for (int r = 0; r < 4; ++r) {
        #pragma unroll
        for (int o = 1; o < 16; o <<= 1)
          tmax[r] = fmaxf(tmax[r], __shfl_xor(tmax[r], o));
      }
      float lsum2[4] = {0.f, 0.f, 0.f, 0.f};
      #pragma unroll
      for (int ni = 0; ni < 8; ++ni)
        #pragma unroll
        for (int r = 0; r < 4; ++r) {
          float e = expf(acc[mi][ni][r] - tmax[r]);
          acc[mi][ni][r] = e;
          lsum2[r] += e;
        }
      #pragma unroll
      for (int r = 0; r < 4; ++r) {
        #pragma unroll
        for (int o = 1; o < 16; o <<= 1)
          lsum2[r] += __shfl_xor(lsum2[r], o);
        lsum2[r] = 1.f / lsum2[r];
      }
      #pragma unroll
      for (int ni = 0; ni < 8; ++ni) {
        int m = ni * 16 + l15;
        #pragma unroll
        for (int r = 0; r < 4; ++r) {
          float p = acc[mi][ni][r] * lsum2[r];
          o2[(long)(w * 32 + mi * 16 + lg4 * 4 + r) * NL + m] = (f16)p;
          colp[ni] += p;
        }
      }
    }
    #pragma unroll
    for (int ni = 0; ni < 8; ++ni) {
      colp[ni] += __shfl_xor(colp[ni], 16);
      colp[ni] += __shfl_xor(colp[ni], 32);
    }
    if (lg4 == 0) {
      #pragma unroll
      for (int ni = 0; ni < 8; ++ni)
        colpart[w * 128 + ni * 16 + l15] = colp[ni];
    }
    __syncthreads();
    if (tid < 128) {
      float cs = colpart[tid] + colpart[128 + tid] + colpart[256 + tid] + colpart[384 + tid];
      float wm = cs;
      #pragma unroll
      for (int o = 32; o; o >>= 1) wm = fmaxf(wm, __shfl_xor(wm, o));
      if ((tid & 63) == 0) colpart[512 + (tid >> 6)] = wm;
    }
    __syncthreads();
    if (tid == 0) colmax[z] = fmaxf(colpart[512], colpart[513]);
  }
}

// ---------------------------------------------------------------- inverse (MFMA fp16 NS, 8 waves)
__global__ __launch_bounds__(512) void k_inverse(
    const f16* __restrict__ k2h, const float* __restrict__ colmax,
    const float* __restrict__ partU, const float* __restrict__ partML,
    float* __restrict__ m2)
{
  __shared__ __align__(16) f16 bufA[128 * 128];
  __shared__ __align__(16) f16 bufB[128 * 128];
  __shared__ __align__(16) f16 Vt[128 * 128];
  __shared__ __align__(16) f16 Pt[128 * 128];
  int z = blockIdx.x;
  int tid = threadIdx.x;
  int w = tid >> 6, l = tid & 63;
  int l15 = l & 15, lg4 = l >> 4;
  int wr = (w >> 1) * 32, wc = (w & 1) * 64;

  float cv = colmax[l];
  #pragma unroll
  for (int o = 32; o; o >>= 1) cv = fmaxf(cv, __shfl_xor(cv, o));
  float recip = 1.f / cv;

  const f16* key = k2h + (long)z * NL * NL;
  auto swz = [](int r, int c) { return r * 128 + ((((c >> 3) ^ (r & 15))) << 3) + (c & 7); };

  for (int idx = tid; idx < 128 * 16; idx += 512) {
    int r = idx >> 4, c8 = (idx & 15) << 3;
    f16x8 kk = *(const f16x8*)&key[r * 128 + c8];
    f16x8 sv;
    #pragma unroll
    for (int j = 0; j < 8; ++j) sv[j] = (f16)(recip * (float)kk[j]);
    *(f16x8*)&Vt[swz(r, c8)] = sv;
    #pragma unroll
    for (int j = 0; j < 8; ++j) bufA[swz(c8 + j, r)] = sv[j];
  }
  __syncthreads();

  f16* Vc = bufA;
  f16* Sc = bufB;

  f32x4 acc[2][4];
  auto MMc = [&](bool fromGlobal, const f16* Aimg, const f16* Bimg) {
    #pragma unroll
    for (int mi = 0; mi < 2; ++mi)
      #pragma unroll
      for (int ni = 0; ni < 4; ++ni) acc[mi][ni] = (f32x4){0.f, 0.f, 0.f, 0.f};
    #pragma unroll
    for (int ks = 0; ks < 4; ++ks) {
      int k0 = ks * 32 + lg4 * 8;
      f16x8 bf[4];
      #pragma unroll
      for (int ni = 0; ni < 4; ++ni)
        bf[ni] = *(const f16x8*)&Bimg[swz(wc + ni * 16 + l15, k0)];
      f16x8 af[2];
      if (fromGlobal) {
        af[0] = *(const f16x8*)&key[(wr + l15) * 128 + k0];
        af[1] = *(const f16x8*)&key[(wr + 16 + l15) * 128 + k0];
      } else {
        af[0] = *(const f16x8*)&Aimg[swz(wr + l15, k0)];
        af[1] = *(const f16x8*)&Aimg[swz(wr + 16 + l15, k0)];
      }
      #pragma unroll
      for (int mi = 0; mi < 2; ++mi)
        #pragma unroll
        for (int ni = 0; ni < 4; ++ni)
          acc[mi][ni] = __builtin_amdgcn_mfma_f32_16x16x32_f16(af[mi], bf[ni], acc[mi][ni], 0, 0, 0);
    }
  };
  auto store = [&](f16* Nout, f16* Tout, float aT, float bT) {
    #pragma unroll
    for (int mi = 0; mi < 2; ++mi) {
      int row0 = wr + mi * 16 + lg4 * 4;
      #pragma unroll
      for (int ni = 0; ni < 4; ++ni) {
        int col = wc + ni * 16 + l15;
        f16x4 tv;
        #pragma unroll
        for (int r = 0; r < 4; ++r) {
          float v = acc[mi][ni][r];
          if (Nout) Nout[swz(row0 + r, col)] = (f16)v;
          tv[r] = (f16)(aT * v + ((row0 + r == col) ? bT : 0.f));
        }
        *(f16x4*)&Tout[col * 128 + ((((row0 >> 3) ^ (col & 15))) << 3) + (row0 & 7)] = tv;
      }
    }
  };

  for (int it = 0; it < 6; ++it) {
    MMc(true, nullptr, Vt);  store(Sc, Pt, -1.f, 7.f);       __syncthreads();
    MMc(false, Sc, Pt);      store(nullptr, Vt, -1.f, 15.f); __syncthreads();
    MMc(false, Sc, Vt);      store(nullptr, Pt, -0.25f, 3.25f); __syncthreads();
    MMc(false, Vc, Pt);      store(Sc, Vt, 1.f, 0.f);        __syncthreads();
    f16* tsw = Vc; Vc = Sc; Sc = tsw;
  }

  for (int idx = tid; idx < 128 * 16; idx += 512) {
    int q = idx >> 4, c4 = (idx & 15) << 2;
    long base = ((long)z * NL + q) * NSPL;
    float m[NSPL], lv[NSPL];
    #pragma unroll
    for (int c = 0; c < NSPL; ++c) {
      m[c] = partML[(base + c) * 2];
      lv[c] = partML[(base + c) * 2 + 1];
    }
    float M = fmaxf(fmaxf(m[0], m[1]), fmaxf(m[2], m[3]));
    float L = 0.f, scf[NSPL];
    #pragma unroll
    for (int c = 0; c < NSPL; ++c) {
      scf[c] = expf(m[c] - M);
      L += lv[c] * scf[c];
    }
    float4 o = make_float4(0.f, 0.f, 0.f, 0.f);
    #pragma unroll
    for (int c = 0; c < NSPL; ++c) {
      float4 u = *(const float4*)&partU[(base + c) * 64 + c4];
      o.x += scf[c] * u.x; o.y += scf[c] * u.y;
      o.z += scf[c] * u.z; o.w += scf[c] * u.w;
    }
    float invL = 1.f / L;
    Pt[swz(c4 + 0, q)] = (f16)(o.x * invL);
    Pt[swz(c4 + 1, q)] = (f16)(o.y * invL);
    Pt[swz(c4 + 2, q)] = (f16)(o.z * invL);
    Pt[swz(c4 + 3, q)] = (f16)(o.w * invL);
  }
  __syncthreads();
  f32x4 accF[4];
  #pragma unroll
  for (int ni = 0; ni < 4; ++ni) accF[ni] = (f32x4){0.f, 0.f, 0.f, 0.f};
  #pragma unroll
  for (int ks = 0; ks < 4; ++ks) {
    int k0 = ks * 32 + lg4 * 8;
    f16x8 af = *(const f16x8*)&Vc[swz(w * 16 + l15, k0)];
    #pragma unroll
    for (int ni = 0; ni < 4; ++ni) {
      f16x8 bf = *(const f16x8*)&Pt[swz(ni * 16 + l15, k0)];
      accF[ni] = __builtin_amdgcn_mfma_f32_16x16x32_f16(af, bf, accF[ni], 0, 0, 0);
    }
  }
  float* mp = m2 + (long)z * NL * VF;
  #pragma unroll
  for (int ni = 0; ni < 4; ++ni)
    #pragma unroll
    for (int r = 0; r < 4; ++r)
      mp[(long)(w * 16 + lg4 * 4 + r) * VF + ni * 16 + l15] = accF[ni][r];
}

// ---------------------------------------------------------------- kernel_1 + attn + merge (MFMA)
__global__ __launch_bounds__(256, 2) void k_k1attn(
    const f16* __restrict__ Eq16, const f16* __restrict__ kland16,
    const float* __restrict__ aggL, const float* __restrict__ m2,
    const float* __restrict__ proj, f16* __restrict__ merged)
{
  __shared__ __align__(16) f16 Kl[128 * 64];
  __shared__ __align__(16) f16 M2t[64 * 128];
  __shared__ __align__(16) f16 Pb[4 * 16 * 128];
  int zz = blockIdx.x;
  int z = zz >> 5, st = zz & 31;
  int b = z >> 3, h = z & 7;
  int s0 = st * 64;
  int tid = threadIdx.x;
  int w = tid >> 6, l = tid & 63;
  int l15 = l & 15, lg4 = l >> 4, l7 = l & 7;
  float sigma = fabsf(aggL[h]) + 0.001f;
  float cpos = -sigma * (1.f / 16.f);

  for (int c = tid; c < 128 * 8; c += 256) {
    int k = c >> 3, kc = c & 7;
    f16x8 v = *(const f16x8*)&kland16[((long)b * NL + k) * 64 + kc * 8];
    *(f16x8*)&Kl[k * 64 + ((kc ^ (k & 7)) << 3)] = v;
  }
  const float* mp = m2 + (long)z * NL * VF;
  for (int c = tid; c < 128 * 16; c += 256) {
    int k = c >> 4, c4 = (c & 15) << 2;
    float4 v4 = *(const float4*)&mp[k * 64 + c4];
    int kc = k >> 3, ki = k & 7;
    M2t[(c4 + 0) * 128 + ((kc ^ ((c4 + 0) & 7)) << 3) + ki] = (f16)v4.x;
    M2t[(c4 + 1) * 128 + ((kc ^ ((c4 + 1) & 7)) << 3) + ki] = (f16)v4.y;
    M2t[(c4 + 2) * 128 + ((kc ^ ((c4 + 2) & 7)) << 3) + ki] = (f16)v4.z;
    M2t[(c4 + 3) * 128 + ((kc ^ ((c4 + 3) & 7)) << 3) + ki] = (f16)v4.w;
  }
  __syncthreads();

  long qrow = (long)z * S + s0 + w * 16 + l15;
  f16x8 af[2];
  #pragma unroll
  for (int kh = 0; kh < 2; ++kh)
    af[kh] = *(const f16x8*)&Eq16[qrow * 64 + kh * 32 + lg4 * 8];

  f32x4 sc[8];
  #pragma unroll
  for (int ct = 0; ct < 8; ++ct) {
    int n = ct * 16 + l15;
    f16x8 b0 = *(const f16x8*)&Kl[n * 64 + ((lg4 ^ (n & 7)) << 3)];
    f16x8 b1 = *(const f16x8*)&Kl[n * 64 + (((4 + lg4) ^ (n & 7)) << 3)];
    f32x4 zz4 = (f32x4){0.f, 0.f, 0.f, 0.f};
    zz4 = __builtin_amdgcn_mfma_f32_16x16x32_f16(af[0], b0, zz4, 0, 0, 0);
    sc[ct] = __builtin_amdgcn_mfma_f32_16x16x32_f16(af[1], b1, zz4, 0, 0, 0);
  }
  float tmax[4] = {-INFINITY, -INFINITY, -INFINITY, -INFINITY};
  #pragma unroll
  for (int ct = 0; ct < 8; ++ct) {
    int lm = ct * 16 + l15;
    #pragma unroll
    for (int r = 0; r < 4; ++r) {
      int spos = s0 + w * 16 + lg4 * 4 + r;
      float a = (float)(spos - 16 * lm);
      float ac = fminf(fmaxf(a, 0.f), 15.f);
      float dd = fabsf(a - ac);
      float sum = ac * ac - 15.f * ac + 120.f + 16.f * dd;
      float s = sc[ct][r] + cpos * sum;
      sc[ct][r] = s;
      tmax[r] = fmaxf(tmax[r], s);
    }
  }
  #pragma unroll
  for (int r = 0; r < 4; ++r) {
    #pragma unroll
    for (int o = 1; o < 16; o <<= 1)
      tmax[r] = fmaxf(tmax[r], __shfl_xor(tmax[r], o));
  }
  float lsum[4] = {0.f, 0.f, 0.f, 0.f};
  #pragma unroll
  for (int ct = 0; ct < 8; ++ct) {
    #pragma unroll
    for (int r = 0; r < 4; ++r) {
      float p = expf(sc[ct][r] - tmax[r]);
      sc[ct][r] = p;
      lsum[r] += p;
    }
  }
  #pragma unroll
  for (int r = 0; r < 4; ++r) {
    #pragma unroll
    for (int o = 1; o < 16; o <<= 1)
      lsum[r] += __shfl_xor(lsum[r], o);
    lsum[r] = 1.f / lsum[r];
  }
  f16* Pw = &Pb[w * 16 * 128];
  #pragma unroll
  for (int ct = 0; ct < 8; ++ct) {
    int kc = ct * 2 + (l15 >> 3);
    int ki = l15 & 7;
    #pragma unroll
    for (int r = 0; r < 4; ++r) {
      int row = lg4 * 4 + r;
      Pw[row * 128 + ((kc ^ (row & 7)) << 3) + ki] = (f16)(sc[ct][r] * lsum[r]);
    }
  }
  f32x4 Oa[4];
  #pragma unroll
  for (int i = 0; i < 4; ++i) Oa[i] = (f32x4){0.f, 0.f, 0.f, 0.f};
  #pragma unroll
  for (int ks = 0; ks < 4; ++ks) {
    f16x8 pa = *(const f16x8*)&Pw[l15 * 128 + (((ks * 4 + lg4) ^ l7) << 3)];
    #pragma unroll
    for (int dt = 0; dt < 4; ++dt) {
      int n = dt * 16 + l15;
      f16x8 bv = *(const f16x8*)&M2t[n * 128 + (((ks * 4 + lg4) ^ (n & 7)) << 3)];
      Oa[dt] = __builtin_amdgcn_mfma_f32_16x16x32_f16(pa, bv, Oa[dt], 0, 0, 0);
    }
  }
  #pragma unroll
  for (int r = 0; r < 4; ++r) {
    long srow = (long)b * S + s0 + w * 16 + lg4 * 4 + r;
    int r7 = (int)(srow & 7);
    #pragma unroll
    for (int dt = 0; dt < 4; ++dt) {
      int col = dt * 16 + l15;
      float v = Oa[dt][r] + proj[srow * VF + col];
      merged[srow * (long)HV + h * 64 + (((col >> 3) ^ r7) << 3) + (col & 7)] = (f16)v;
    }
  }
}

} // namespace

extern "C" void kernel_launch(void* const* d_in, const int* in_sizes, int n_in,
                              void* d_out, int out_size, void* d_ws, size_t ws_size,
                              hipStream_t stream)
{
  const float* lat   = (const float*)d_in[0];
  const float* masks = (const float*)d_in[1];
  const float* xemb  = (const float*)d_in[2];
  const float* ccls  = (const float*)d_in[4];
  const float* qlin  = (const float*)d_in[5];
  const float* klin  = (const float*)d_in[6];
  const float* vlin  = (const float*)d_in[7];
  const float* plin  = (const float*)d_in[8];
  const float* agg   = (const float*)d_in[9];
  const float* cfeat = (const float*)d_in[10];
  float* out = (float*)d_out;
  float* ws = (float*)d_ws;

  long off = 0;
  auto allocF = [&](long n) { float* p = ws + off; off += (n + 3) & ~3L; return p; };
  auto allocH = [&](long n) { f16* p = (f16*)(ws + off); off += ((n + 1) / 2 + 3) & ~3L; return p; };

  f16* origA = allocH(ROWS * KSF);
  f16* vbufA = allocH(ROWS * KSF);
  f16* merged = allocH(ROWS * (long)HV);
  f16* WQt = allocH(16L * 64 * KSF);
  f16* WKt = allocH(2L * 64 * KSF);
  f16* WVt = allocH(16L * 64 * KSF);
  f16* WPt = allocH(2L * 64 * KSF);
  f16* WCFt = allocH((long)KSF * 512);
  f16* WCCt = allocH(64L * 512);
  f16* Ek16 = allocH((long)B * S * 64);
  f16* Ev16 = allocH((long)B * H * S * 64);
  f16* Eq16 = allocH((long)B * H * S * 64);
  f16* qland16 = allocH((long)B * H * NL * DF);
  f16* kland16 = allocH((long)B * NL * DF);
  f16* k2h = allocH((long)B * H * NL * NL);
  float* cl     = allocF(ROWS * HS);
  float* projb  = allocF((long)B * S * VF);
  float* m2b    = allocF((long)B * H * NL * VF);
  float* colmax = allocF(64);
  float* partU  = allocF((long)B * H * NL * NSPL * 64);
  float* partML = allocF((long)B * H * NL * NSPL * 2);

  k_cl<<<(int)(ROWS / 4), 256, 0, stream>>>(lat, masks, cl);
  k_prep<<<10752 + 1864, 256, 0, stream>>>(xemb, cl, qlin, klin, vlin, plin,
      cfeat, ccls, origA, WQt, WKt, WVt, WPt, WCFt, WCCt);

  const f16* Aact = origA;
  for (int layer = 0; layer < 2; ++layer) {
    const f16* wq = WQt + (long)layer * 8 * 64 * KSF;
    const f16* wk = WKt + (long)layer * 64 * KSF;
    const f16* wvv = WVt + (long)layer * 8 * 64 * KSF;
    const f16* wp = WPt + (long)layer * 64 * KSF;
    const float* bq = qlin + (long)layer * 8 * FEATP * 64 + (long)(FEATP - 2) * 64;
    const float* bk = klin + (long)layer * FEATP * 64 + (long)(FEATP - 2) * 64;
    const float* bv = vlin + (long)layer * 8 * FEATP * 64 + (long)(FEATP - 2) * 64;
    const float* bp = plin + (long)layer * FEATP * 64 + (long)(FEATP - 2) * 64;
    const float* ag = agg + layer * H;

    k_qve<<<1280, 256, 0, stream>>>(Aact, origA, wq, wvv, wk, wp,
        bq, bv, bk, bp, Eq16, Ev16, Ek16, projb, qland16, kland16);

    k_land<<<576, 256, 0, stream>>>(qland16, kland16, Ek16, Ev16, ag, masks,
        partU, partML, k2h, colmax);
    k_inverse<<<B * H, 512, 0, stream>>>(k2h, colmax, partU, partML, m2b);
    k_k1attn<<<B * H * (S / 64), 256, 0, stream>>>(Eq16, kland16, ag, m2b, projb, merged);

    if (layer == 0) {
      dim3 gC(64, 21, 1);
      k_mgemm<<<gC, 256, 0, stream>>>(merged, 0, 1, WCFt, 0, 1, 8, 1,
          nullptr, 0, 0, nullptr, 0, 1.0f, vbufA, FEAT, nullptr);
      Aact = vbufA;
    } else {
      dim3 gO(64, 1, 1);
      k_mgemm<<<gO, 256, 0, stream>>>(merged, 0, 1, WCCt, 0, 1, 8, 2,
          out, 0, HS, nullptr, 0, 1.0f, nullptr, HS, masks);
    }
  }
  (void)in_sizes; (void)n_in; (void)out_size; (void)ws_size;
}

// Round 26
// 427.596 us; speedup vs baseline: 1.0148x; 1.0148x over previous
//
#include <hip/hip_runtime.h>
#include <math.h>

// ESMMimicryModule: B=8 S=2048 H=8 NL=128 DF=VF=64 NF=1280 HS=33 FEAT=1313
// Round 26: REVERT to Round-24 (427.4us best). R25's producer-side V-transpose
// created a 16-way LDS bank conflict in k_qve's epilogue (column read of
// row-major st; SQ_LDS_BANK_CONFLICT 688K->4.55M) and regressed 427->434.
// k_land keeps scatter-transpose V staging; k_qve writes Ev row-wise.

namespace {

constexpr int B = 8, S = 2048, H = 8, NL = 128, DF = 64, VF = 64;
constexpr int NF = 1280, HS = 33, FEAT = 1313, FEATP = 1314;
constexpr int SEG = 16, HV = H * VF;            // 512
constexpr int KSF = 1344;                        // padded feature-K (21*64)
constexpr int NSPL = 4;                          // key chunks in split-S flash
constexpr long ROWS = (long)B * S;               // 16384
constexpr float INV_SCALE = 0.35355339059327373f;

typedef _Float16 f16;
typedef _Float16 f16x8 __attribute__((ext_vector_type(8)));
typedef _Float16 f16x4 __attribute__((ext_vector_type(4)));
typedef float f32x4 __attribute__((ext_vector_type(4)));

// ---------------------------------------------------------------- cl = softmax(latent)*mask
__global__ __launch_bounds__(256) void k_cl(
    const float* __restrict__ lat, const float* __restrict__ masks,
    float* __restrict__ cl)
{
  long row = (long)blockIdx.x * 4 + (threadIdx.x >> 6);
  int l = threadIdx.x & 63;
  float v = (l < HS) ? lat[row * HS + l] : -INFINITY;
  float m = v;
  #pragma unroll
  for (int o = 32; o; o >>= 1) m = fmaxf(m, __shfl_xor(m, o));
  float e = (l < HS) ? expf(v - m) : 0.f;
  float s = e;
  #pragma unroll
  for (int o = 32; o; o >>= 1) s += __shfl_xor(s, o);
  if (l < HS) cl[row * HS + l] = e / s * masks[row];
}

// ---------------------------------------------------------------- prep: origA arena + 6 weight arenas
// blocks 0..10751: cvta body ; 10752..12615: cvtw6 body
__global__ __launch_bounds__(256) void k_prep(
    const float* __restrict__ xemb, const float* __restrict__ cl,
    const float* __restrict__ qlin, const float* __restrict__ klin,
    const float* __restrict__ vlin, const float* __restrict__ plin,
    const float* __restrict__ cfeat, const float* __restrict__ ccls,
    f16* __restrict__ origA,
    f16* __restrict__ WQt, f16* __restrict__ WKt, f16* __restrict__ WVt,
    f16* __restrict__ WPt, f16* __restrict__ WCFt, f16* __restrict__ WCCt)
{
  long bid = blockIdx.x;
  int tid = threadIdx.x;
  if (bid < 10752) {
    long idx = bid * 256 + tid;        // chunk id (row, c)
    long row = idx / 168;
    int c = (int)(idx - row * 168);
    int t = c >> 3, cs = c & 7;        // SOURCE chunk
    int k0 = t * 64 + cs * 8;
    f16x8 v;
    if (t < 20) {
      float4 a = *(const float4*)&xemb[row * NF + k0];
      float4 b = *(const float4*)&xemb[row * NF + k0 + 4];
      v[0] = (f16)a.x; v[1] = (f16)a.y; v[2] = (f16)a.z; v[3] = (f16)a.w;
      v[4] = (f16)b.x; v[5] = (f16)b.y; v[6] = (f16)b.z; v[7] = (f16)b.w;
    } else {
      #pragma unroll
      for (int i = 0; i < 8; ++i) {
        int k = k0 + i;
        float f = 0.f;
        if (k < NF) f = xemb[row * NF + k];
        else if (k < FEAT) f = cl[row * HS + (k - NF)];
        v[i] = (f16)f;
      }
    }
    int cd = cs ^ ((int)row & 7);
    *(f16x8*)&origA[row * KSF + t * 64 + cd * 8] = v;
  } else {
    constexpr long s1 = 172032, s2 = 193536, s3 = 365568, s4 = 387072,
                   s5 = 473088, s6 = 477184;
    long idx = (bid - 10752) * 256 + tid;
    if (idx >= s6) return;
    const float* src; f16* dst; int K, N, Npad, KS; long srcZ, rel;
    if (idx < s1)      { src = qlin;  dst = WQt;  K = FEAT; N = 64;  Npad = 64;  KS = KSF; srcZ = (long)FEATP * 64; rel = idx; }
    else if (idx < s2) { src = klin;  dst = WKt;  K = FEAT; N = 64;  Npad = 64;  KS = KSF; srcZ = (long)FEATP * 64; rel = idx - s1; }
    else if (idx < s3) { src = vlin;  dst = WVt;  K = FEAT; N = 64;  Npad = 64;  KS = KSF; srcZ = (long)FEATP * 64; rel = idx - s2; }
    else if (idx < s4) { src = plin;  dst = WPt;  K = FEAT; N = 64;  Npad = 64;  KS = KSF; srcZ = (long)FEATP * 64; rel = idx - s3; }
    else if (idx < s5) { src = cfeat; dst = WCFt; K = 512;  N = FEAT; Npad = KSF; KS = 512; srcZ = 0; rel = idx - s4; }
    else               { src = ccls;  dst = WCCt; K = 512;  N = HS;  Npad = 64;  KS = 512; srcZ = 0; rel = idx - s5; }
    long cpz = (long)Npad * (KS >> 3);
    long z = rel / cpz;
    long rem = rel - z * cpz;
    int n = (int)(rem / (KS >> 3));
    int c = (int)(rem - (long)n * (KS >> 3));
    int t = c >> 3, cs = c & 7;
    int cd = cs ^ (n & 7);
    int k0 = t * 64 + cd * 8;
    const float* sp = src + z * srcZ;
    f16x8 v;
    #pragma unroll
    for (int i = 0; i < 8; ++i) {
      int k = k0 + i;
      v[i] = (f16)((k < K && n < N) ? sp[(long)k * N + n] : 0.f);
    }
    *(f16x8*)&dst[rel * 8] = v;
  }
}

// ---------------------------------------------------------------- fp16 MFMA GEMM (generic)
// mode 1: fp16 swizzled arena (KSF stride, zero-fill col>=NR), LDS-staged
// mode 2: fp32 out * mask, col<NR
__global__ __launch_bounds__(256, 2) void k_mgemm(
    const f16* __restrict__ A, long aZOff, int aDiv,
    const f16* __restrict__ Wt, long wZOff, int wMod,
    int KT, int mode,
    float* __restrict__ C, long cZOff, int ldC,
    const float* __restrict__ biasBase, long biasZOff, float scale,
    f16* __restrict__ outA, int NR, const float* __restrict__ mask)
{
  const long KS = (long)KT * 64;
  int z = blockIdx.z;
  const f16* Ap = A + (long)(z / aDiv) * aZOff;
  const f16* Wp = Wt + (long)(z % wMod) * wZOff;
  long m0 = (long)blockIdx.x * 256;
  int n0 = blockIdx.y * 64;
  constexpr int BOFF = 256 * 64;
  __shared__ f16 lds[2][(256 + 64) * 64];
  int tid = threadIdx.x;
  int wv = tid >> 6, l = tid & 63;

  const f16* aW = Ap + (m0 + wv * 64 + (l >> 3)) * KS + (l & 7) * 8;
  const f16* bW = Wp + ((long)(n0 + wv * 16 + (l >> 3))) * KS + (l & 7) * 8;

  f32x4 acc[4][4];
  #pragma unroll
  for (int i = 0; i < 4; ++i)
    #pragma unroll
    for (int j = 0; j < 4; ++j) acc[i][j] = (f32x4){0.f, 0.f, 0.f, 0.f};

  auto stage = [&](int buf, int t) {
    f16* la = &lds[buf][(wv * 64) * 64];
    const f16* ga = aW + (long)t * 64;
    #pragma unroll
    for (int j = 0; j < 8; ++j)
      __builtin_amdgcn_global_load_lds(
          (const __attribute__((address_space(1))) void*)(ga + (long)j * 8 * KS),
          (__attribute__((address_space(3))) void*)(la + j * 8 * 64), 16, 0, 0);
    f16* lb = &lds[buf][BOFF + (wv * 16) * 64];
    const f16* gb = bW + (long)t * 64;
    #pragma unroll
    for (int j = 0; j < 2; ++j)
      __builtin_amdgcn_global_load_lds(
          (const __attribute__((address_space(1))) void*)(gb + (long)j * 8 * KS),
          (__attribute__((address_space(3))) void*)(lb + j * 8 * 64), 16, 0, 0);
  };

  stage(0, 0);
  int rA = (wv * 64 + (l & 15)) * 64;
  int rB = BOFF + (l & 15) * 64;
  int lc = l >> 4, lx = l & 7;
  for (int t = 0; t < KT; ++t) {
    int nb = t & 1;
    if (t + 1 < KT) {
      stage(nb ^ 1, t + 1);
      asm volatile("s_waitcnt vmcnt(10)" ::: "memory");
    } else {
      asm volatile("s_waitcnt vmcnt(0)" ::: "memory");
    }
    __syncthreads();
    const f16* base = &lds[nb][0];
    f16x8 af[4][2], bf[4][2];
    #pragma unroll
    for (int mi = 0; mi < 4; ++mi)
      #pragma unroll
      for (int kh = 0; kh < 2; ++kh)
        af[mi][kh] = *(const f16x8*)&base[rA + mi * 16 * 64 + (((kh * 4 + lc) ^ lx) << 3)];
    #pragma unroll
    for (int ni = 0; ni < 4; ++ni)
      #pragma unroll
      for (int kh = 0; kh < 2; ++kh)
        bf[ni][kh] = *(const f16x8*)&base[rB + ni * 16 * 64 + (((kh * 4 + lc) ^ lx) << 3)];
    #pragma unroll
    for (int mi = 0; mi < 4; ++mi)
      #pragma unroll
      for (int ni = 0; ni < 4; ++ni) {
        acc[mi][ni] = __builtin_amdgcn_mfma_f32_16x16x32_f16(af[mi][0], bf[ni][0], acc[mi][ni], 0, 0, 0);
        acc[mi][ni] = __builtin_amdgcn_mfma_f32_16x16x32_f16(af[mi][1], bf[ni][1], acc[mi][ni], 0, 0, 0);
      }
    __syncthreads();
  }

  int lr = (l >> 4) * 4;
  int lcn = l & 15;
  if (mode == 2) {
    #pragma unroll
    for (int mi = 0; mi < 4; ++mi) {
      #pragma unroll
      for (int r = 0; r < 4; ++r) {
        long row = m0 + wv * 64 + mi * 16 + lr + r;
        float mv = mask[row];
        #pragma unroll
        for (int ni = 0; ni < 4; ++ni) {
          int col = n0 + ni * 16 + lcn;
          if (col < NR) C[row * (long)ldC + col] = acc[mi][ni][r] * mv;
        }
      }
    }
  } else {  // mode 1
    f16* st = &lds[0][0];
    #pragma unroll
    for (int ni = 0; ni < 4; ++ni) {
      int coll = ni * 16 + lcn;
      int col = n0 + coll;
      bool ok = col < NR;
      #pragma unroll
      for (int mi = 0; mi < 4; ++mi) {
        int rowl = wv * 64 + mi * 16 + lr;
        #pragma unroll
        for (int r = 0; r < 4; ++r) {
          float v = ok ? acc[mi][ni][r] * scale : 0.f;
          st[(rowl + r) * 64 + coll] = (f16)v;
        }
      }
    }
    __syncthreads();
    int tt = n0 >> 6;
    for (int c = tid; c < 2048; c += 256) {
      int row = c >> 3, cd = c & 7;
      long grow = m0 + row;
      int r7 = (int)grow & 7;
      f16x8 v = *(const f16x8*)&st[row * 64 + cd * 8];
      *(f16x8*)&outA[grow * KSF + tt * 64 + ((cd ^ r7) << 3)] = v;
    }
  }
}

// ---------------------------------------------------------------- merged Eq+Ev | Ek+proj launch
// Single-buffered (m97 structure): 32KB LDS -> 4-5 blocks/CU.
__global__ __launch_bounds__(256, 2) void k_qve(
    const f16* __restrict__ Aact, const f16* __restrict__ Aorig,
    const f16* __restrict__ WQl, const f16* __restrict__ WVl,
    const f16* __restrict__ wk, const f16* __restrict__ wp,
    const float* __restrict__ bqBase, const float* __restrict__ bvBase,
    const float* __restrict__ bk, const float* __restrict__ bp,
    f16* __restrict__ Eq16, f16* __restrict__ Ev16, f16* __restrict__ Ek16,
    float* __restrict__ projb,
    f16* __restrict__ qland16, f16* __restrict__ kland16)
{
  constexpr int KT = 21;
  __shared__ __align__(16) f16 shbuf[256 * 64];   // 32 KB single buffer
  int bid = blockIdx.x;
  int tid = threadIdx.x;
  int wv = tid >> 6, l = tid & 63;
  int l15 = l & 15, lc = l >> 4, lx = l & 7;
  int lr = (l >> 4) * 4;
  int lcn = l & 15;

  if (bid < 1024) {
    // ================= Eq+Ev body =================
    constexpr int BOFF = 128 * 64;
    int z = bid >> 4;                 // b*H + h
    int h = z & 7;
    const f16* Ap = Aact + (long)(z >> 3) * S * KSF;
    const f16* wqp = WQl + (long)h * 64 * KSF;
    const f16* wvp = WVl + (long)h * 64 * KSF;
    const float* bq = bqBase + (long)h * FEATP * 64;
    const float* bv = bvBase + (long)h * FEATP * 64;
    long m0 = (long)(bid & 15) * 128;

    const f16* aW = Ap + (m0 + wv * 32 + (l >> 3)) * KSF + (l & 7) * 8;

    f32x4 acc[2][8];
    #pragma unroll
    for (int i = 0; i < 2; ++i)
      #pragma unroll
      for (int j = 0; j < 8; ++j) acc[i][j] = (f32x4){0.f, 0.f, 0.f, 0.f};

    auto stage = [&](int t) {
      f16* la = &shbuf[(wv * 32) * 64];
      const f16* ga = aW + (long)t * 64;
      #pragma unroll
      for (int j = 0; j < 4; ++j)
        __builtin_amdgcn_global_load_lds(
            (const __attribute__((address_space(1))) void*)(ga + (long)j * 8 * KSF),
            (__attribute__((address_space(3))) void*)(la + j * 512), 16, 0, 0);
      f16* lb = &shbuf[BOFF + (wv * 32) * 64];
      #pragma unroll
      for (int j = 0; j < 4; ++j) {
        int brow = wv * 32 + j * 8 + (l >> 3);
        const f16* src = (brow < 64 ? wqp + (long)brow * KSF
                                    : wvp + (long)(brow - 64) * KSF)
                         + (l & 7) * 8 + (long)t * 64;
        __builtin_amdgcn_global_load_lds(
            (const __attribute__((address_space(1))) void*)src,
            (__attribute__((address_space(3))) void*)(lb + j * 512), 16, 0, 0);
      }
    };

    for (int t = 0; t < KT; ++t) {
      stage(t);
      asm volatile("s_waitcnt vmcnt(0)" ::: "memory");
      __syncthreads();
      const f16* base = &shbuf[0];
      f16x8 af[2][2], bf[8][2];
      #pragma unroll
      for (int mi = 0; mi < 2; ++mi)
        #pragma unroll
        for (int kh = 0; kh < 2; ++kh)
          af[mi][kh] = *(const f16x8*)&base[(wv * 32 + mi * 16 + l15) * 64 + (((kh * 4 + lc) ^ lx) << 3)];
      #pragma unroll
      for (int ni = 0; ni < 8; ++ni) {
        int n = ni * 16 + l15;
        #pragma unroll
        for (int kh = 0; kh < 2; ++kh)
          bf[ni][kh] = *(const f16x8*)&base[BOFF + n * 64 + (((kh * 4 + lc) ^ (n & 7)) << 3)];
      }
      #pragma unroll
      for (int mi = 0; mi < 2; ++mi)
        #pragma unroll
        for (int ni = 0; ni < 8; ++ni) {
          acc[mi][ni] = __builtin_amdgcn_mfma_f32_16x16x32_f16(af[mi][0], bf[ni][0], acc[mi][ni], 0, 0, 0);
          acc[mi][ni] = __builtin_amdgcn_mfma_f32_16x16x32_f16(af[mi][1], bf[ni][1], acc[mi][ni], 0, 0, 0);
        }
      __syncthreads();
    }

    f16* st = &shbuf[0];
    #pragma unroll
    for (int ni = 0; ni < 8; ++ni) {
      int col = ni * 16 + l15;
      float bvv = (col < 64) ? bq[col] : bv[col - 64];
      float scl = (col < 64) ? INV_SCALE : 1.f;
      #pragma unroll
      for (int mi = 0; mi < 2; ++mi) {
        int rowl = wv * 32 + mi * 16 + lr;
        #pragma unroll
        for (int r = 0; r < 4; ++r)
          st[(rowl + r) * 128 + col] = (f16)((acc[mi][ni][r] + bvv) * scl);
      }
    }
    __syncthreads();
    f16* oq = Eq16 + (long)z * S * 64;
    f16* ov = Ev16 + (long)z * S * 64;
    for (int c = tid; c < 1024; c += 256) {
      int rw = c >> 3, cc = c & 7;
      *(f16x8*)&oq[(m0 + rw) * 64 + cc * 8] = *(const f16x8*)&st[rw * 128 + cc * 8];
      *(f16x8*)&ov[(m0 + rw) * 64 + cc * 8] = *(const f16x8*)&st[rw * 128 + 64 + cc * 8];
    }
    for (int c = tid; c < 512; c += 256) {
      int lm = c >> 6, d = c & 63;
      float s = 0.f;
      #pragma unroll
      for (int i = 0; i < SEG; ++i) s += (float)st[(lm * SEG + i) * 128 + d];
      float v = s * (1.f / SEG);
      long li = (long)z * NL + (m0 >> 4) + lm;
      qland16[li * 64 + d] = (f16)v;
    }
  } else {
    // ================= Ek / proj body (BM=128) =================
    constexpr int BOFF = 128 * 64;
    int rel = bid - 1024;
    int zz2 = rel >> 4;
    int prob = zz2 >> 3, b = zz2 & 7;
    const f16* Ap = (prob ? Aorig : Aact) + (long)b * S * KSF;
    const f16* Wp = prob ? wp : wk;
    long m0 = (long)(rel & 15) * 128;

    const f16* aW = Ap + (m0 + wv * 32 + (l >> 3)) * KSF + (l & 7) * 8;
    const f16* bW = Wp + ((long)(wv * 16 + (l >> 3))) * KSF + (l & 7) * 8;

    f32x4 acc[2][4];
    #pragma unroll
    for (int i = 0; i < 2; ++i)
      #pragma unroll
      for (int j = 0; j < 4; ++j) acc[i][j] = (f32x4){0.f, 0.f, 0.f, 0.f};

    auto stage = [&](int t) {
      f16* la = &shbuf[(wv * 32) * 64];
      const f16* ga = aW + (long)t * 64;
      #pragma unroll
      for (int j = 0; j < 4; ++j)
        __builtin_amdgcn_global_load_lds(
            (const __attribute__((address_space(1))) void*)(ga + (long)j * 8 * KSF),
            (__attribute__((address_space(3))) void*)(la + j * 512), 16, 0, 0);
      f16* lb = &shbuf[BOFF + (wv * 16) * 64];
      const f16* gb = bW + (long)t * 64;
      #pragma unroll
      for (int j = 0; j < 2; ++j)
        __builtin_amdgcn_global_load_lds(
            (const __attribute__((address_space(1))) void*)(gb + (long)j * 8 * KSF),
            (__attribute__((address_space(3))) void*)(lb + j * 512), 16, 0, 0);
    };

    for (int t = 0; t < KT; ++t) {
      stage(t);
      asm volatile("s_waitcnt vmcnt(0)" ::: "memory");
      __syncthreads();
      const f16* base = &shbuf[0];
      f16x8 af[2][2], bf[4][2];
      #pragma unroll
      for (int mi = 0; mi < 2; ++mi)
        #pragma unroll
        for (int kh = 0; kh < 2; ++kh)
          af[mi][kh] = *(const f16x8*)&base[(wv * 32 + mi * 16 + l15) * 64 + (((kh * 4 + lc) ^ lx) << 3)];
      #pragma unroll
      for (int ni = 0; ni < 4; ++ni)
        #pragma unroll
        for (int kh = 0; kh < 2; ++kh)
          bf[ni][kh] = *(const f16x8*)&base[BOFF + (ni * 16 + l15) * 64 + (((kh * 4 + lc) ^ lx) << 3)];
      #pragma unroll
      for (int mi = 0; mi < 2; ++mi)
        #pragma unroll
        for (int ni = 0; ni < 4; ++ni) {
          acc[mi][ni] = __builtin_amdgcn_mfma_f32_16x16x32_f16(af[mi][0], bf[ni][0], acc[mi][ni], 0, 0, 0);
          acc[mi][ni] = __builtin_amdgcn_mfma_f32_16x16x32_f16(af[mi][1], bf[ni][1], acc[mi][ni], 0, 0, 0);
        }
      __syncthreads();
    }

    if (prob == 0) {
      f16* st = &shbuf[0];
      #pragma unroll
      for (int ni = 0; ni < 4; ++ni) {
        int col = ni * 16 + lcn;
        float bv = bk[col];
        #pragma unroll
        for (int mi = 0; mi < 2; ++mi) {
          int rowl = wv * 32 + mi * 16 + lr;
          #pragma unroll
          for (int r = 0; r < 4; ++r)
            st[(rowl + r) * 64 + col] = (f16)((acc[mi][ni][r] + bv) * INV_SCALE);
        }
      }
      __syncthreads();
      f16* o16 = Ek16 + (long)b * S * 64;
      for (int c = tid; c < 1024; c += 256) {
        int row = c >> 3, cc = c & 7;
        f16x8 v = *(const f16x8*)&st[row * 64 + cc * 8];
        *(f16x8*)&o16[(m0 + row) * 64 + cc * 8] = v;
      }
      for (int c = tid; c < 512; c += 256) {
        int lm = c >> 6, d = c & 63;
        float s = 0.f;
        #pragma unroll
        for (int i = 0; i < SEG; ++i) s += (float)st[(lm * SEG + i) * 64 + d];
        float v = s * (1.f / SEG);
        long li = (long)b * NL + (m0 >> 4) + lm;
        kland16[li * 64 + d] = (f16)v;
      }
    } else {
      float* Cp = projb + (long)b * S * 64;
      #pragma unroll
      for (int ni = 0; ni < 4; ++ni) {
        int col = ni * 16 + lcn;
        float bv = bp[col];
        #pragma unroll
        for (int mi = 0; mi < 2; ++mi) {
          long row = m0 + wv * 32 + mi * 16 + lr;
          #pragma unroll
          for (int r = 0; r < 4; ++r)
            Cp[(row + r) * 64 + col] = (acc[mi][ni][r] + bv) * 0.5f;
        }
      }
    }
  }
}

// ---------------------------------------------------------------- merged kernel_3 | kernel_2
// blocks 0..511: flash (Q frags in regs, K/V staged; 49.7KB -> 3 blocks/CU).
// blocks 512..575: kernel2 MFMA.
__global__ __launch_bounds__(256, 3) void k_land(
    const f16* __restrict__ qland16, const f16* __restrict__ kland16,
    const f16* __restrict__ Ek16, const f16* __restrict__ Ev16,
    const float* __restrict__ aggL, const float* __restrict__ masks,
    float* __restrict__ partU, float* __restrict__ partML,
    f16* __restrict__ k2h, float* __restrict__ colmax)
{
  __shared__ __align__(16) unsigned char smem[49664];
  int bid = blockIdx.x;
  int tid = threadIdx.x;
  int w = tid >> 6, l = tid & 63;
  int l15 = l & 15, lg4 = l >> 4, l7 = l & 7;

  if (bid < 512) {
    // ================= kernel3 body =================
    f16* Ks = (f16*)smem;                    // 128*64 = 16 KB
    f16* Vt = (f16*)(smem + 16384);          // 64*128 = 16 KB
    f16* Pb = (f16*)(smem + 32768);          // 4*16*128 = 16 KB
    float* Ms = (float*)(smem + 49152);      // 128 floats
    int chunk = bid & (NSPL - 1);
    int z2 = bid >> 2;
    int z = z2 >> 1, half = z2 & 1;
    int b = z >> 3, h = z & 7;
    int q0 = half * 64;
    float sigma = fabsf(aggL[h]) + 0.001f;
    float cpos = -sigma * (1.f / 16.f);

    // loop-invariant Q fragments straight from global (R21-proven safe)
    f16x8 af[2];
    #pragma unroll
    for (int kh = 0; kh < 2; ++kh)
      af[kh] = *(const f16x8*)&qland16[((long)z * NL + q0 + w * 16 + l15) * 64 + kh * 32 + lg4 * 8];

    f16* Pw = &Pb[w * 16 * 128];
    f32x4 Oa[4];
    #pragma unroll
    for (int i = 0; i < 4; ++i) Oa[i] = (f32x4){0.f, 0.f, 0.f, 0.f};
    float mrun[4] = {-INFINITY, -INFINITY, -INFINITY, -INFINITY};
    float lrun[4] = {0.f, 0.f, 0.f, 0.f};

    int t0beg = chunk * (S / 128 / NSPL), t0end = t0beg + S / 128 / NSPL;
    for (int t0 = t0beg; t0 < t0end; ++t0) {
      __syncthreads();
      for (int c = tid; c < 1024; c += 256) {
        int k = c >> 3, kc = c & 7;
        f16x8 v = *(const f16x8*)&Ek16[((long)b * S + t0 * 128 + k) * 64 + kc * 8];
        *(f16x8*)&Ks[k * 64 + ((kc ^ (k & 7)) << 3)] = v;
      }
      for (int c = tid; c < 1024; c += 256) {
        int k = c & 127, dc = c >> 7;
        f16x8 v = *(const f16x8*)&Ev16[((long)z * S + t0 * 128 + k) * 64 + dc * 8];
        int kc = k >> 3, ki = k & 7;
        #pragma unroll
        for (int j = 0; j < 8; ++j) {
          int d = dc * 8 + j;
          Vt[d * 128 + ((kc ^ (d & 7)) << 3) + ki] = v[j];
        }
      }
      if (tid < 128)
        Ms[tid] = (masks[(long)b * S + t0 * 128 + tid] == 0.f) ? -1e6f : 0.f;
      __syncthreads();

      f32x4 sc[8];
      #pragma unroll
      for (int ct = 0; ct < 8; ++ct) {
        int n = ct * 16 + l15;
        f16x8 b0 = *(const f16x8*)&Ks[n * 64 + (((lg4) ^ (n & 7)) << 3)];
        f16x8 b1 = *(const f16x8*)&Ks[n * 64 + (((4 + lg4) ^ (n & 7)) << 3)];
        f32x4 zz = (f32x4){0.f, 0.f, 0.f, 0.f};
        zz = __builtin_amdgcn_mfma_f32_16x16x32_f16(af[0], b0, zz, 0, 0, 0);
        sc[ct] = __builtin_amdgcn_mfma_f32_16x16x32_f16(af[1], b1, zz, 0, 0, 0);
      }
      float tmax[4] = {-INFINITY, -INFINITY, -INFINITY, -INFINITY};
      #pragma unroll
      for (int ct = 0; ct < 8; ++ct) {
        float mk = Ms[ct * 16 + l15];
        int key = t0 * 128 + ct * 16 + l15;
        #pragma unroll
        for (int r = 0; r < 4; ++r) {
          int qg = q0 + w * 16 + lg4 * 4 + r;
          float a = (float)(key - 16 * qg);
          float ac = fminf(fmaxf(a, 0.f), 15.f);
          float dd = fabsf(a - ac);
          float sum = ac * ac - 15.f * ac + 120.f + 16.f * dd;
          float s = sc[ct][r] + cpos * sum + mk;
          sc[ct][r] = s;
          tmax[r] = fmaxf(tmax[r], s);
        }
      }
      #pragma unroll
      for (int r = 0; r < 4; ++r) {
        #pragma unroll
        for (int o = 1; o < 16; o <<= 1)
          tmax[r] = fmaxf(tmax[r], __shfl_xor(tmax[r], o));
      }
      float fr[4], lsum[4];
      #pragma unroll
      for (int r = 0; r < 4; ++r) {
        float mnew = fmaxf(mrun[r], tmax[r]);
        fr[r] = expf(mrun[r] - mnew);
        mrun[r] = mnew;
        lsum[r] = 0.f;
      }
      #pragma unroll
      for (int ct = 0; ct < 8; ++ct) {
        #pragma unroll
        for (int r = 0; r < 4; ++r) {
          float p = expf(sc[ct][r] - mrun[r]);
          sc[ct][r] = p;
          lsum[r] += p;
        }
      }
      #pragma unroll
      for (int r = 0; r < 4; ++r) {
        #pragma unroll
        for (int o = 1; o < 16; o <<= 1)
          lsum[r] += __shfl_xor(lsum[r], o);
        lrun[r] = lrun[r] * fr[r] + lsum[r];
      }
      f32x4 fv = (f32x4){fr[0], fr[1], fr[2], fr[3]};
      #pragma unroll
      for (int dt = 0; dt < 4; ++dt) Oa[dt] *= fv;
      #pragma unroll
      for (int ct = 0; ct < 8; ++ct) {
        int kc = ct * 2 + (l15 >> 3);
        int ki = l15 & 7;
        #pragma unroll
        for (int r = 0; r < 4; ++r) {
          int row = lg4 * 4 + r;
          Pw[row * 128 + ((kc ^ (row & 7)) << 3) + ki] = (f16)sc[ct][r];
        }
      }
      #pragma unroll
      for (int ks = 0; ks < 4; ++ks) {
        f16x8 pa = *(const f16x8*)&Pw[l15 * 128 + (((ks * 4 + lg4) ^ l7) << 3)];
        #pragma unroll
        for (int dt = 0; dt < 4; ++dt) {
          int n = dt * 16 + l15;
          f16x8 bv = *(const f16x8*)&Vt[n * 128 + (((ks * 4 + lg4) ^ (n & 7)) << 3)];
          Oa[dt] = __builtin_amdgcn_mfma_f32_16x16x32_f16(pa, bv, Oa[dt], 0, 0, 0);
        }
      }
    }
    #pragma unroll
    for (int r = 0; r < 4; ++r) {
      long qg = q0 + w * 16 + lg4 * 4 + r;
      long base = ((long)z * NL + qg) * NSPL + chunk;
      #pragma unroll
      for (int dt = 0; dt < 4; ++dt)
        partU[base * 64 + dt * 16 + l15] = Oa[dt][r];
      if (l15 == 0) {
        partML[base * 2] = mrun[r];
        partML[base * 2 + 1] = lrun[r];
      }
    }
  } else {
    // ================= kernel2 body (MFMA) =================
    f16* Qs2 = (f16*)smem;                   // 128*64
    f16* Ks2 = (f16*)(smem + 16384);         // 128*64
    float* colpart = (float*)(smem + 32768); // 516 floats
    int z = bid - 512;
    int b2 = z >> 3, h2 = z & 7;
    float sigma = fabsf(aggL[h2]) + 0.001f;
    for (int c = tid; c < 1024; c += 256) {
      int q = c >> 3, kc = c & 7;
      f16x8 v = *(const f16x8*)&qland16[((long)z * NL + q) * 64 + kc * 8];
      *(f16x8*)&Qs2[q * 64 + ((kc ^ (q & 7)) << 3)] = v;
      f16x8 u = *(const f16x8*)&kland16[((long)b2 * NL + q) * 64 + kc * 8];
      *(f16x8*)&Ks2[q * 64 + ((kc ^ (q & 7)) << 3)] = u;
    }
    __syncthreads();
    f32x4 acc[2][8];
    #pragma unroll
    for (int i = 0; i < 2; ++i)
      #pragma unroll
      for (int j = 0; j < 8; ++j) acc[i][j] = (f32x4){0.f, 0.f, 0.f, 0.f};
    f16x8 af[2][2];
    #pragma unroll
    for (int mi = 0; mi < 2; ++mi)
      #pragma unroll
      for (int kh = 0; kh < 2; ++kh)
        af[mi][kh] = *(const f16x8*)&Qs2[(w * 32 + mi * 16 + l15) * 64 + (((kh * 4 + lg4) ^ l7) << 3)];
    #pragma unroll
    for (int ni = 0; ni < 8; ++ni) {
      int n = ni * 16 + l15;
      f16x8 b0 = *(const f16x8*)&Ks2[n * 64 + ((lg4 ^ (n & 7)) << 3)];
      f16x8 b1 = *(const f16x8*)&Ks2[n * 64 + (((4 + lg4) ^ (n & 7)) << 3)];
      #pragma unroll
      for (int mi = 0; mi < 2; ++mi) {
        acc[mi][ni] = __builtin_amdgcn_mfma_f32_16x16x32_f16(af[mi][0], b0, acc[mi][ni], 0, 0, 0);
        acc[mi][ni] = __builtin_amdgcn_mfma_f32_16x16x32_f16(af[mi][1], b1, acc[mi][ni], 0, 0, 0);
      }
    }
    // pos term + row softmax + k2h store + col partials
    float colp[8];
    #pragma unroll
    for (int ni = 0; ni < 8; ++ni) colp[ni] = 0.f;
    f16* o2 = k2h + (long)z * NL * NL;
    #pragma unroll
    for (int mi = 0; mi < 2; ++mi) {
      float tmax[4] = {-INFINITY, -INFINITY, -INFINITY, -INFINITY};
      #pragma unroll
      for (int ni = 0; ni < 8; ++ni) {
        int m = ni * 16 + l15;
        #pragma unroll
        for (int r = 0; r < 4; ++r) {
          int row = w * 32 + mi * 16 + lg4 * 4 + r;
          float dd = fabsf((float)(row - m));
          float s = acc[mi][ni][r] - sigma * ((row == m) ? 5.3125f : 16.f * dd);
          acc[mi][ni][r] = s;
          tmax[r] = fmaxf(tmax[r], s);
        }
      }
      #pragma unroll
      for (int r = 0; r < 4; ++r) {
        #pragma unroll
        for (int o = 1; o < 16; o <<= 1)
          tmax[r] = fmaxf(tmax[r], __shfl_xor(tmax[r], o));
      }
      float lsum2[4] = {0.f, 0.f, 0.f, 0.f};
      #pragma unroll
      for (int ni = 0; ni < 8; ++ni)
        #pragma unroll
        for (int r = 0; r < 4; ++r) {
          float e = expf(acc[mi][ni][r] - tmax[r]);
          acc[mi][ni][r] = e;
          lsum2[r] += e;
        }
      #pragma unroll
      for (int r = 0; r < 4; ++r) {
        #pragma unroll
        for (int o = 1; o < 16; o <<= 1)
          lsum2[r] += __shfl_xor(lsum2[r], o);
        lsum2[r] = 1.f / lsum2[r];
      }
      #pragma unroll
      for (int ni = 0; ni < 8; ++ni) {
        int m = ni * 16 + l15;
        #pragma unroll
        for (int r = 0; r < 4; ++r) {
          float p = acc[mi][ni][r] * lsum2[r];
          o2[(long)(w * 32 + mi * 16 + lg4 * 4 + r) * NL + m] = (f16)p;
          colp[ni] += p;
        }
      }
    }
    #pragma unroll
    for (int ni = 0; ni < 8; ++ni) {
      colp[ni] += __shfl_xor(colp[ni], 16);
      colp[ni] += __shfl_xor(colp[ni], 32);
    }
    if (lg4 == 0) {
      #pragma unroll
      for (int ni = 0; ni < 8; ++ni)
        colpart[w * 128 + ni * 16 + l15] = colp[ni];
    }
    __syncthreads();
    if (tid < 128) {
      float cs = colpart[tid] + colpart[128 + tid] + colpart[256 + tid] + colpart[384 + tid];
      float wm = cs;
      #pragma unroll
      for (int o = 32; o; o >>= 1) wm = fmaxf(wm, __shfl_xor(wm, o));
      if ((tid & 63) == 0) colpart[512 + (tid >> 6)] = wm;
    }
    __syncthreads();
    if (tid == 0) colmax[z] = fmaxf(colpart[512], colpart[513]);
  }
}

// ---------------------------------------------------------------- inverse (MFMA fp16 NS, 8 waves)
__global__ __launch_bounds__(512) void k_inverse(
    const f16* __restrict__ k2h, const float* __restrict__ colmax,
    const float* __restrict__ partU, const float* __restrict__ partML,
    float* __restrict__ m2)
{
  __shared__ __align__(16) f16 bufA[128 * 128];
  __shared__ __align__(16) f16 bufB[128 * 128];
  __shared__ __align__(16) f16 Vt[128 * 128];
  __shared__ __align__(16) f16 Pt[128 * 128];
  int z = blockIdx.x;
  int tid = threadIdx.x;
  int w = tid >> 6, l = tid & 63;
  int l15 = l & 15, lg4 = l >> 4;
  int wr = (w >> 1) * 32, wc = (w & 1) * 64;

  float cv = colmax[l];
  #pragma unroll
  for (int o = 32; o; o >>= 1) cv = fmaxf(cv, __shfl_xor(cv, o));
  float recip = 1.f / cv;

  const f16* key = k2h + (long)z * NL * NL;
  auto swz = [](int r, int c) { return r * 128 + ((((c >> 3) ^ (r & 15))) << 3) + (c & 7); };

  for (int idx = tid; idx < 128 * 16; idx += 512) {
    int r = idx >> 4, c8 = (idx & 15) << 3;
    f16x8 kk = *(const f16x8*)&key[r * 128 + c8];
    f16x8 sv;
    #pragma unroll
    for (int j = 0; j < 8; ++j) sv[j] = (f16)(recip * (float)kk[j]);
    *(f16x8*)&Vt[swz(r, c8)] = sv;
    #pragma unroll
    for (int j = 0; j < 8; ++j) bufA[swz(c8 + j, r)] = sv[j];
  }
  __syncthreads();

  f16* Vc = bufA;
  f16* Sc = bufB;

  f32x4 acc[2][4];
  auto MMc = [&](bool fromGlobal, const f16* Aimg, const f16* Bimg) {
    #pragma unroll
    for (int mi = 0; mi < 2; ++mi)
      #pragma unroll
      for (int ni = 0; ni < 4; ++ni) acc[mi][ni] = (f32x4){0.f, 0.f, 0.f, 0.f};
    #pragma unroll
    for (int ks = 0; ks < 4; ++ks) {
      int k0 = ks * 32 + lg4 * 8;
      f16x8 bf[4];
      #pragma unroll
      for (int ni = 0; ni < 4; ++ni)
        bf[ni] = *(const f16x8*)&Bimg[swz(wc + ni * 16 + l15, k0)];
      f16x8 af[2];
      if (fromGlobal) {
        af[0] = *(const f16x8*)&key[(wr + l15) * 128 + k0];
        af[1] = *(const f16x8*)&key[(wr + 16 + l15) * 128 + k0];
      } else {
        af[0] = *(const f16x8*)&Aimg[swz(wr + l15, k0)];
        af[1] = *(const f16x8*)&Aimg[swz(wr + 16 + l15, k0)];
      }
      #pragma unroll
      for (int mi = 0; mi < 2; ++mi)
        #pragma unroll
        for (int ni = 0; ni < 4; ++ni)
          acc[mi][ni] = __builtin_amdgcn_mfma_f32_16x16x32_f16(af[mi], bf[ni], acc[mi][ni], 0, 0, 0);
    }
  };
  auto store = [&](f16* Nout, f16* Tout, float aT, float bT) {
    #pragma unroll
    for (int mi = 0; mi < 2; ++mi) {
      int row0 = wr + mi * 16 + lg4 * 4;
      #pragma unroll
      for (int ni = 0; ni < 4; ++ni) {
        int col = wc + ni * 16 + l15;
        f16x4 tv;
        #pragma unroll
        for (int r = 0; r < 4; ++r) {
          float v = acc[mi][ni][r];
          if (Nout) Nout[swz(row0 + r, col)] = (f16)v;
          tv[r] = (f16)(aT * v + ((row0 + r == col) ? bT : 0.f));
        }
        *(f16x4*)&Tout[col * 128 + ((((row0 >> 3) ^ (col & 15))) << 3) + (row0 & 7)] = tv;
      }
    }
  };

  for (int it = 0; it < 6; ++it) {
    MMc(true, nullptr, Vt);  store(Sc, Pt, -1.f, 7.f);       __syncthreads();
    MMc(false, Sc, Pt);      store(nullptr, Vt, -1.f, 15.f); __syncthreads();
    MMc(false, Sc, Vt);      store(nullptr, Pt, -0.25f, 3.25f); __syncthreads();
    MMc(false, Vc, Pt);      store(Sc, Vt, 1.f, 0.f);        __syncthreads();
    f16* tsw = Vc; Vc = Sc; Sc = tsw;
  }

  for (int idx = tid; idx < 128 * 16; idx += 512) {
    int q = idx >> 4, c4 = (idx & 15) << 2;
    long base = ((long)z * NL + q) * NSPL;
    float m[NSPL], lv[NSPL];
    #pragma unroll
    for (int c = 0; c < NSPL; ++c) {
      m[c] = partML[(base + c) * 2];
      lv[c] = partML[(base + c) * 2 + 1];
    }
    float M = fmaxf(fmaxf(m[0], m[1]), fmaxf(m[2], m[3]));
    float L = 0.f, scf[NSPL];
    #pragma unroll
    for (int c = 0; c < NSPL; ++c) {
      scf[c] = expf(m[c] - M);
      L += lv[c] * scf[c];
    }
    float4 o = make_float4(0.f, 0.f, 0.f, 0.f);
    #pragma unroll
    for (int c = 0; c < NSPL; ++c) {
      float4 u = *(const float4*)&partU[(base + c) * 64 + c4];
      o.x += scf[c] * u.x; o.y += scf[c] * u.y;
      o.z += scf[c] * u.z; o.w += scf[c] * u.w;
    }
    float invL = 1.f / L;
    Pt[swz(c4 + 0, q)] = (f16)(o.x * invL);
    Pt[swz(c4 + 1, q)] = (f16)(o.y * invL);
    Pt[swz(c4 + 2, q)] = (f16)(o.z * invL);
    Pt[swz(c4 + 3, q)] = (f16)(o.w * invL);
  }
  __syncthreads();
  f32x4 accF[4];
  #pragma unroll
  for (int ni = 0; ni < 4; ++ni) accF[ni] = (f32x4){0.f, 0.f, 0.f, 0.f};
  #pragma unroll
  for (int ks = 0; ks < 4; ++ks) {
    int k0 = ks * 32 + lg4 * 8;
    f16x8 af = *(const f16x8*)&Vc[swz(w * 16 + l15, k0)];
    #pragma unroll
    for (int ni = 0; ni < 4; ++ni) {
      f16x8 bf = *(const f16x8*)&Pt[swz(ni * 16 + l15, k0)];
      accF[ni] = __builtin_amdgcn_mfma_f32_16x16x32_f16(af, bf, accF[ni], 0, 0, 0);
    }
  }
  float* mp = m2 + (long)z * NL * VF;
  #pragma unroll
  for (int ni = 0; ni < 4; ++ni)
    #pragma unroll
    for (int r = 0; r < 4; ++r)
      mp[(long)(w * 16 + lg4 * 4 + r) * VF + ni * 16 + l15] = accF[ni][r];
}

// ---------------------------------------------------------------- kernel_1 + attn + merge (MFMA)
__global__ __launch_bounds__(256, 2) void k_k1attn(
    const f16* __restrict__ Eq16, const f16* __restrict__ kland16,
    const float* __restrict__ aggL, const float* __restrict__ m2,
    const float* __restrict__ proj, f16* __restrict__ merged)
{
  __shared__ __align__(16) f16 Kl[128 * 64];
  __shared__ __align__(16) f16 M2t[64 * 128];
  __shared__ __align__(16) f16 Pb[4 * 16 * 128];
  int zz = blockIdx.x;
  int z = zz >> 5, st = zz & 31;
  int b = z >> 3, h = z & 7;
  int s0 = st * 64;
  int tid = threadIdx.x;
  int w = tid >> 6, l = tid & 63;
  int l15 = l & 15, lg4 = l >> 4, l7 = l & 7;
  float sigma = fabsf(aggL[h]) + 0.001f;
  float cpos = -sigma * (1.f / 16.f);

  for (int c = tid; c < 128 * 8; c += 256) {
    int k = c >> 3, kc = c & 7;
    f16x8 v = *(const f16x8*)&kland16[((long)b * NL + k) * 64 + kc * 8];
    *(f16x8*)&Kl[k * 64 + ((kc ^ (k & 7)) << 3)] = v;
  }
  const float* mp = m2 + (long)z * NL * VF;
  for (int c = tid; c < 128 * 16; c += 256) {
    int k = c >> 4, c4 = (c & 15) << 2;
    float4 v4 = *(const float4*)&mp[k * 64 + c4];
    int kc = k >> 3, ki = k & 7;
    M2t[(c4 + 0) * 128 + ((kc ^ ((c4 + 0) & 7)) << 3) + ki] = (f16)v4.x;
    M2t[(c4 + 1) * 128 + ((kc ^ ((c4 + 1) & 7)) << 3) + ki] = (f16)v4.y;
    M2t[(c4 + 2) * 128 + ((kc ^ ((c4 + 2) & 7)) << 3) + ki] = (f16)v4.z;
    M2t[(c4 + 3) * 128 + ((kc ^ ((c4 + 3) & 7)) << 3) + ki] = (f16)v4.w;
  }
  __syncthreads();

  long qrow = (long)z * S + s0 + w * 16 + l15;
  f16x8 af[2];
  #pragma unroll
  for (int kh = 0; kh < 2; ++kh)
    af[kh] = *(const f16x8*)&Eq16[qrow * 64 + kh * 32 + lg4 * 8];

  f32x4 sc[8];
  #pragma unroll
  for (int ct = 0; ct < 8; ++ct) {
    int n = ct * 16 + l15;
    f16x8 b0 = *(const f16x8*)&Kl[n * 64 + ((lg4 ^ (n & 7)) << 3)];
    f16x8 b1 = *(const f16x8*)&Kl[n * 64 + (((4 + lg4) ^ (n & 7)) << 3)];
    f32x4 zz4 = (f32x4){0.f, 0.f, 0.f, 0.f};
    zz4 = __builtin_amdgcn_mfma_f32_16x16x32_f16(af[0], b0, zz4, 0, 0, 0);
    sc[ct] = __builtin_amdgcn_mfma_f32_16x16x32_f16(af[1], b1, zz4, 0, 0, 0);
  }
  float tmax[4] = {-INFINITY, -INFINITY, -INFINITY, -INFINITY};
  #pragma unroll
  for (int ct = 0; ct < 8; ++ct) {
    int lm = ct * 16 + l15;
    #pragma unroll
    for (int r = 0; r < 4; ++r) {
      int spos = s0 + w * 16 + lg4 * 4 + r;
      float a = (float)(spos - 16 * lm);
      float ac = fminf(fmaxf(a, 0.f), 15.f);
      float dd = fabsf(a - ac);
      float sum = ac * ac - 15.f * ac + 120.f + 16.f * dd;
      float s = sc[ct][r] + cpos * sum;
      sc[ct][r] = s;
      tmax[r] = fmaxf(tmax[r], s);
    }
  }
  #pragma unroll
  for (int r = 0; r < 4; ++r) {
    #pragma unroll
    for (int o = 1; o < 16; o <<= 1)
      tmax[r] = fmaxf(tmax[r], __shfl_xor(tmax[r], o));
  }
  float lsum[4] = {0.f, 0.f, 0.f, 0.f};
  #pragma unroll
  for (int ct = 0; ct < 8; ++ct) {
    #pragma unroll
    for (int r = 0; r < 4; ++r) {
      float p = expf(sc[ct][r] - tmax[r]);
      sc[ct][r] = p;
      lsum[r] += p;
    }
  }
  #pragma unroll
  for (int r = 0; r < 4; ++r) {
    #pragma unroll
    for (int o = 1; o < 16; o <<= 1)
      lsum[r] += __shfl_xor(lsum[r], o);
    lsum[r] = 1.f / lsum[r];
  }
  f16* Pw = &Pb[w * 16 * 128];
  #pragma unroll
  for (int ct = 0; ct < 8; ++ct) {
    int kc = ct * 2 + (l15 >> 3);
    int ki = l15 & 7;
    #pragma unroll
    for (int r = 0; r < 4; ++r) {
      int row = lg4 * 4 + r;
      Pw[row * 128 + ((kc ^ (row & 7)) << 3) + ki] = (f16)(sc[ct][r] * lsum[r]);
    }
  }
  f32x4 Oa[4];
  #pragma unroll
  for (int i = 0; i < 4; ++i) Oa[i] = (f32x4){0.f, 0.f, 0.f, 0.f};
  #pragma unroll
  for (int ks = 0; ks < 4; ++ks) {
    f16x8 pa = *(const f16x8*)&Pw[l15 * 128 + (((ks * 4 + lg4) ^ l7) << 3)];
    #pragma unroll
    for (int dt = 0; dt < 4; ++dt) {
      int n = dt * 16 + l15;
      f16x8 bv = *(const f16x8*)&M2t[n * 128 + (((ks * 4 + lg4) ^ (n & 7)) << 3)];
      Oa[dt] = __builtin_amdgcn_mfma_f32_16x16x32_f16(pa, bv, Oa[dt], 0, 0, 0);
    }
  }
  #pragma unroll
  for (int r = 0; r < 4; ++r) {
    long srow = (long)b * S + s0 + w * 16 + lg4 * 4 + r;
    int r7 = (int)(srow & 7);
    #pragma unroll
    for (int dt = 0; dt < 4; ++dt) {
      int col = dt * 16 + l15;
      float v = Oa[dt][r] + proj[srow * VF + col];
      merged[srow * (long)HV + h * 64 + (((col >> 3) ^ r7) << 3) + (col & 7)] = (f16)v;
    }
  }
}

} // namespace

extern "C" void kernel_launch(void* const* d_in, const int* in_sizes, int n_in,
                              void* d_out, int out_size, void* d_ws, size_t ws_size,
                              hipStream_t stream)
{
  const float* lat   = (const float*)d_in[0];
  const float* masks = (const float*)d_in[1];
  const float* xemb  = (const float*)d_in[2];
  const float* ccls  = (const float*)d_in[4];
  const float* qlin  = (const float*)d_in[5];
  const float* klin  = (const float*)d_in[6];
  const float* vlin  = (const float*)d_in[7];
  const float* plin  = (const float*)d_in[8];
  const float* agg   = (const float*)d_in[9];
  const float* cfeat = (const float*)d_in[10];
  float* out = (float*)d_out;
  float* ws = (float*)d_ws;

  long off = 0;
  auto allocF = [&](long n) { float* p = ws + off; off += (n + 3) & ~3L; return p; };
  auto allocH = [&](long n) { f16* p = (f16*)(ws + off); off += ((n + 1) / 2 + 3) & ~3L; return p; };

  f16* origA = allocH(ROWS * KSF);
  f16* vbufA = allocH(ROWS * KSF);
  f16* merged = allocH(ROWS * (long)HV);
  f16* WQt = allocH(16L * 64 * KSF);
  f16* WKt = allocH(2L * 64 * KSF);
  f16* WVt = allocH(16L * 64 * KSF);
  f16* WPt = allocH(2L * 64 * KSF);
  f16* WCFt = allocH((long)KSF * 512);
  f16* WCCt = allocH(64L * 512);
  f16* Ek16 = allocH((long)B * S * 64);
  f16* Ev16 = allocH((long)B * H * S * 64);
  f16* Eq16 = allocH((long)B * H * S * 64);
  f16* qland16 = allocH((long)B * H * NL * DF);
  f16* kland16 = allocH((long)B * NL * DF);
  f16* k2h = allocH((long)B * H * NL * NL);
  float* cl     = allocF(ROWS * HS);
  float* projb  = allocF((long)B * S * VF);
  float* m2b    = allocF((long)B * H * NL * VF);
  float* colmax = allocF(64);
  float* partU  = allocF((long)B * H * NL * NSPL * 64);
  float* partML = allocF((long)B * H * NL * NSPL * 2);

  k_cl<<<(int)(ROWS / 4), 256, 0, stream>>>(lat, masks, cl);
  k_prep<<<10752 + 1864, 256, 0, stream>>>(xemb, cl, qlin, klin, vlin, plin,
      cfeat, ccls, origA, WQt, WKt, WVt, WPt, WCFt, WCCt);

  const f16* Aact = origA;
  for (int layer = 0; layer < 2; ++layer) {
    const f16* wq = WQt + (long)layer * 8 * 64 * KSF;
    const f16* wk = WKt + (long)layer * 64 * KSF;
    const f16* wvv = WVt + (long)layer * 8 * 64 * KSF;
    const f16* wp = WPt + (long)layer * 64 * KSF;
    const float* bq = qlin + (long)layer * 8 * FEATP * 64 + (long)(FEATP - 2) * 64;
    const float* bk = klin + (long)layer * FEATP * 64 + (long)(FEATP - 2) * 64;
    const float* bv = vlin + (long)layer * 8 * FEATP * 64 + (long)(FEATP - 2) * 64;
    const float* bp = plin + (long)layer * FEATP * 64 + (long)(FEATP - 2) * 64;
    const float* ag = agg + layer * H;

    k_qve<<<1280, 256, 0, stream>>>(Aact, origA, wq, wvv, wk, wp,
        bq, bv, bk, bp, Eq16, Ev16, Ek16, projb, qland16, kland16);

    k_land<<<576, 256, 0, stream>>>(qland16, kland16, Ek16, Ev16, ag, masks,
        partU, partML, k2h, colmax);
    k_inverse<<<B * H, 512, 0, stream>>>(k2h, colmax, partU, partML, m2b);
    k_k1attn<<<B * H * (S / 64), 256, 0, stream>>>(Eq16, kland16, ag, m2b, projb, merged);

    if (layer == 0) {
      dim3 gC(64, 21, 1);
      k_mgemm<<<gC, 256, 0, stream>>>(merged, 0, 1, WCFt, 0, 1, 8, 1,
          nullptr, 0, 0, nullptr, 0, 1.0f, vbufA, FEAT, nullptr);
      Aact = vbufA;
    } else {
      dim3 gO(64, 1, 1);
      k_mgemm<<<gO, 256, 0, stream>>>(merged, 0, 1, WCCt, 0, 1, 8, 2,
          out, 0, HS, nullptr, 0, 1.0f, nullptr, HS, masks);
    }
  }
  (void)in_sizes; (void)n_in; (void)out_size; (void)ws_size;
}

// Round 27
// 420.408 us; speedup vs baseline: 1.0322x; 1.0171x over previous
//
#include <hip/hip_runtime.h>
#include <math.h>

// ESMMimicryModule: B=8 S=2048 H=8 NL=128 DF=VF=64 NF=1280 HS=33 FEAT=1313
// Round 27: k_mgemm single-buffered (the R20 lever applied to the last
// double-buffered kernel). LDS 80KB->40KB => ~4 blocks/CU (was 2). Same
// stage->vmcnt(0)->barrier->compute loop as k_qve; MFMA order unchanged ->
// bitwise-identical output. Rest = R26 (= R24 best, 427.4us).

namespace {

constexpr int B = 8, S = 2048, H = 8, NL = 128, DF = 64, VF = 64;
constexpr int NF = 1280, HS = 33, FEAT = 1313, FEATP = 1314;
constexpr int SEG = 16, HV = H * VF;            // 512
constexpr int KSF = 1344;                        // padded feature-K (21*64)
constexpr int NSPL = 4;                          // key chunks in split-S flash
constexpr long ROWS = (long)B * S;               // 16384
constexpr float INV_SCALE = 0.35355339059327373f;

typedef _Float16 f16;
typedef _Float16 f16x8 __attribute__((ext_vector_type(8)));
typedef _Float16 f16x4 __attribute__((ext_vector_type(4)));
typedef float f32x4 __attribute__((ext_vector_type(4)));

// ---------------------------------------------------------------- cl = softmax(latent)*mask
__global__ __launch_bounds__(256) void k_cl(
    const float* __restrict__ lat, const float* __restrict__ masks,
    float* __restrict__ cl)
{
  long row = (long)blockIdx.x * 4 + (threadIdx.x >> 6);
  int l = threadIdx.x & 63;
  float v = (l < HS) ? lat[row * HS + l] : -INFINITY;
  float m = v;
  #pragma unroll
  for (int o = 32; o; o >>= 1) m = fmaxf(m, __shfl_xor(m, o));
  float e = (l < HS) ? expf(v - m) : 0.f;
  float s = e;
  #pragma unroll
  for (int o = 32; o; o >>= 1) s += __shfl_xor(s, o);
  if (l < HS) cl[row * HS + l] = e / s * masks[row];
}

// ---------------------------------------------------------------- prep: origA arena + 6 weight arenas
// blocks 0..10751: cvta body ; 10752..12615: cvtw6 body
__global__ __launch_bounds__(256) void k_prep(
    const float* __restrict__ xemb, const float* __restrict__ cl,
    const float* __restrict__ qlin, const float* __restrict__ klin,
    const float* __restrict__ vlin, const float* __restrict__ plin,
    const float* __restrict__ cfeat, const float* __restrict__ ccls,
    f16* __restrict__ origA,
    f16* __restrict__ WQt, f16* __restrict__ WKt, f16* __restrict__ WVt,
    f16* __restrict__ WPt, f16* __restrict__ WCFt, f16* __restrict__ WCCt)
{
  long bid = blockIdx.x;
  int tid = threadIdx.x;
  if (bid < 10752) {
    long idx = bid * 256 + tid;        // chunk id (row, c)
    long row = idx / 168;
    int c = (int)(idx - row * 168);
    int t = c >> 3, cs = c & 7;        // SOURCE chunk
    int k0 = t * 64 + cs * 8;
    f16x8 v;
    if (t < 20) {
      float4 a = *(const float4*)&xemb[row * NF + k0];
      float4 b = *(const float4*)&xemb[row * NF + k0 + 4];
      v[0] = (f16)a.x; v[1] = (f16)a.y; v[2] = (f16)a.z; v[3] = (f16)a.w;
      v[4] = (f16)b.x; v[5] = (f16)b.y; v[6] = (f16)b.z; v[7] = (f16)b.w;
    } else {
      #pragma unroll
      for (int i = 0; i < 8; ++i) {
        int k = k0 + i;
        float f = 0.f;
        if (k < NF) f = xemb[row * NF + k];
        else if (k < FEAT) f = cl[row * HS + (k - NF)];
        v[i] = (f16)f;
      }
    }
    int cd = cs ^ ((int)row & 7);
    *(f16x8*)&origA[row * KSF + t * 64 + cd * 8] = v;
  } else {
    constexpr long s1 = 172032, s2 = 193536, s3 = 365568, s4 = 387072,
                   s5 = 473088, s6 = 477184;
    long idx = (bid - 10752) * 256 + tid;
    if (idx >= s6) return;
    const float* src; f16* dst; int K, N, Npad, KS; long srcZ, rel;
    if (idx < s1)      { src = qlin;  dst = WQt;  K = FEAT; N = 64;  Npad = 64;  KS = KSF; srcZ = (long)FEATP * 64; rel = idx; }
    else if (idx < s2) { src = klin;  dst = WKt;  K = FEAT; N = 64;  Npad = 64;  KS = KSF; srcZ = (long)FEATP * 64; rel = idx - s1; }
    else if (idx < s3) { src = vlin;  dst = WVt;  K = FEAT; N = 64;  Npad = 64;  KS = KSF; srcZ = (long)FEATP * 64; rel = idx - s2; }
    else if (idx < s4) { src = plin;  dst = WPt;  K = FEAT; N = 64;  Npad = 64;  KS = KSF; srcZ = (long)FEATP * 64; rel = idx - s3; }
    else if (idx < s5) { src = cfeat; dst = WCFt; K = 512;  N = FEAT; Npad = KSF; KS = 512; srcZ = 0; rel = idx - s4; }
    else               { src = ccls;  dst = WCCt; K = 512;  N = HS;  Npad = 64;  KS = 512; srcZ = 0; rel = idx - s5; }
    long cpz = (long)Npad * (KS >> 3);
    long z = rel / cpz;
    long rem = rel - z * cpz;
    int n = (int)(rem / (KS >> 3));
    int c = (int)(rem - (long)n * (KS >> 3));
    int t = c >> 3, cs = c & 7;
    int cd = cs ^ (n & 7);
    int k0 = t * 64 + cd * 8;
    const float* sp = src + z * srcZ;
    f16x8 v;
    #pragma unroll
    for (int i = 0; i < 8; ++i) {
      int k = k0 + i;
      v[i] = (f16)((k < K && n < N) ? sp[(long)k * N + n] : 0.f);
    }
    *(f16x8*)&dst[rel * 8] = v;
  }
}

// ---------------------------------------------------------------- fp16 MFMA GEMM (generic)
// Single-buffered (R20 lever): 40KB LDS -> ~4 blocks/CU.
// mode 1: fp16 swizzled arena (KSF stride, zero-fill col>=NR), LDS-staged
// mode 2: fp32 out * mask, col<NR
__global__ __launch_bounds__(256, 2) void k_mgemm(
    const f16* __restrict__ A, long aZOff, int aDiv,
    const f16* __restrict__ Wt, long wZOff, int wMod,
    int KT, int mode,
    float* __restrict__ C, long cZOff, int ldC,
    const float* __restrict__ biasBase, long biasZOff, float scale,
    f16* __restrict__ outA, int NR, const float* __restrict__ mask)
{
  const long KS = (long)KT * 64;
  int z = blockIdx.z;
  const f16* Ap = A + (long)(z / aDiv) * aZOff;
  const f16* Wp = Wt + (long)(z % wMod) * wZOff;
  long m0 = (long)blockIdx.x * 256;
  int n0 = blockIdx.y * 64;
  constexpr int BOFF = 256 * 64;
  __shared__ f16 lds[(256 + 64) * 64];   // 40 KB single buffer
  int tid = threadIdx.x;
  int wv = tid >> 6, l = tid & 63;

  const f16* aW = Ap + (m0 + wv * 64 + (l >> 3)) * KS + (l & 7) * 8;
  const f16* bW = Wp + ((long)(n0 + wv * 16 + (l >> 3))) * KS + (l & 7) * 8;

  f32x4 acc[4][4];
  #pragma unroll
  for (int i = 0; i < 4; ++i)
    #pragma unroll
    for (int j = 0; j < 4; ++j) acc[i][j] = (f32x4){0.f, 0.f, 0.f, 0.f};

  auto stage = [&](int t) {
    f16* la = &lds[(wv * 64) * 64];
    const f16* ga = aW + (long)t * 64;
    #pragma unroll
    for (int j = 0; j < 8; ++j)
      __builtin_amdgcn_global_load_lds(
          (const __attribute__((address_space(1))) void*)(ga + (long)j * 8 * KS),
          (__attribute__((address_space(3))) void*)(la + j * 8 * 64), 16, 0, 0);
    f16* lb = &lds[BOFF + (wv * 16) * 64];
    const f16* gb = bW + (long)t * 64;
    #pragma unroll
    for (int j = 0; j < 2; ++j)
      __builtin_amdgcn_global_load_lds(
          (const __attribute__((address_space(1))) void*)(gb + (long)j * 8 * KS),
          (__attribute__((address_space(3))) void*)(lb + j * 8 * 64), 16, 0, 0);
  };

  int rA = (wv * 64 + (l & 15)) * 64;
  int rB = BOFF + (l & 15) * 64;
  int lc = l >> 4, lx = l & 7;
  for (int t = 0; t < KT; ++t) {
    stage(t);
    asm volatile("s_waitcnt vmcnt(0)" ::: "memory");
    __syncthreads();
    const f16* base = &lds[0];
    f16x8 af[4][2], bf[4][2];
    #pragma unroll
    for (int mi = 0; mi < 4; ++mi)
      #pragma unroll
      for (int kh = 0; kh < 2; ++kh)
        af[mi][kh] = *(const f16x8*)&base[rA + mi * 16 * 64 + (((kh * 4 + lc) ^ lx) << 3)];
    #pragma unroll
    for (int ni = 0; ni < 4; ++ni)
      #pragma unroll
      for (int kh = 0; kh < 2; ++kh)
        bf[ni][kh] = *(const f16x8*)&base[rB + ni * 16 * 64 + (((kh * 4 + lc) ^ lx) << 3)];
    #pragma unroll
    for (int mi = 0; mi < 4; ++mi)
      #pragma unroll
      for (int ni = 0; ni < 4; ++ni) {
        acc[mi][ni] = __builtin_amdgcn_mfma_f32_16x16x32_f16(af[mi][0], bf[ni][0], acc[mi][ni], 0, 0, 0);
        acc[mi][ni] = __builtin_amdgcn_mfma_f32_16x16x32_f16(af[mi][1], bf[ni][1], acc[mi][ni], 0, 0, 0);
      }
    __syncthreads();
  }

  int lr = (l >> 4) * 4;
  int lcn = l & 15;
  if (mode == 2) {
    #pragma unroll
    for (int mi = 0; mi < 4; ++mi) {
      #pragma unroll
      for (int r = 0; r < 4; ++r) {
        long row = m0 + wv * 64 + mi * 16 + lr + r;
        float mv = mask[row];
        #pragma unroll
        for (int ni = 0; ni < 4; ++ni) {
          int col = n0 + ni * 16 + lcn;
          if (col < NR) C[row * (long)ldC + col] = acc[mi][ni][r] * mv;
        }
      }
    }
  } else {  // mode 1
    f16* st = &lds[0];
    #pragma unroll
    for (int ni = 0; ni < 4; ++ni) {
      int coll = ni * 16 + lcn;
      int col = n0 + coll;
      bool ok = col < NR;
      #pragma unroll
      for (int mi = 0; mi < 4; ++mi) {
        int rowl = wv * 64 + mi * 16 + lr;
        #pragma unroll
        for (int r = 0; r < 4; ++r) {
          float v = ok ? acc[mi][ni][r] * scale : 0.f;
          st[(rowl + r) * 64 + coll] = (f16)v;
        }
      }
    }
    __syncthreads();
    int tt = n0 >> 6;
    for (int c = tid; c < 2048; c += 256) {
      int row = c >> 3, cd = c & 7;
      long grow = m0 + row;
      int r7 = (int)grow & 7;
      f16x8 v = *(const f16x8*)&st[row * 64 + cd * 8];
      *(f16x8*)&outA[grow * KSF + tt * 64 + ((cd ^ r7) << 3)] = v;
    }
  }
}

// ---------------------------------------------------------------- merged Eq+Ev | Ek+proj launch
// Single-buffered (m97 structure): 32KB LDS -> 4-5 blocks/CU.
__global__ __launch_bounds__(256, 2) void k_qve(
    const f16* __restrict__ Aact, const f16* __restrict__ Aorig,
    const f16* __restrict__ WQl, const f16* __restrict__ WVl,
    const f16* __restrict__ wk, const f16* __restrict__ wp,
    const float* __restrict__ bqBase, const float* __restrict__ bvBase,
    const float* __restrict__ bk, const float* __restrict__ bp,
    f16* __restrict__ Eq16, f16* __restrict__ Ev16, f16* __restrict__ Ek16,
    float* __restrict__ projb,
    f16* __restrict__ qland16, f16* __restrict__ kland16)
{
  constexpr int KT = 21;
  __shared__ __align__(16) f16 shbuf[256 * 64];   // 32 KB single buffer
  int bid = blockIdx.x;
  int tid = threadIdx.x;
  int wv = tid >> 6, l = tid & 63;
  int l15 = l & 15, lc = l >> 4, lx = l & 7;
  int lr = (l >> 4) * 4;
  int lcn = l & 15;

  if (bid < 1024) {
    // ================= Eq+Ev body =================
    constexpr int BOFF = 128 * 64;
    int z = bid >> 4;                 // b*H + h
    int h = z & 7;
    const f16* Ap = Aact + (long)(z >> 3) * S * KSF;
    const f16* wqp = WQl + (long)h * 64 * KSF;
    const f16* wvp = WVl + (long)h * 64 * KSF;
    const float* bq = bqBase + (long)h * FEATP * 64;
    const float* bv = bvBase + (long)h * FEATP * 64;
    long m0 = (long)(bid & 15) * 128;

    const f16* aW = Ap + (m0 + wv * 32 + (l >> 3)) * KSF + (l & 7) * 8;

    f32x4 acc[2][8];
    #pragma unroll
    for (int i = 0; i < 2; ++i)
      #pragma unroll
      for (int j = 0; j < 8; ++j) acc[i][j] = (f32x4){0.f, 0.f, 0.f, 0.f};

    auto stage = [&](int t) {
      f16* la = &shbuf[(wv * 32) * 64];
      const f16* ga = aW + (long)t * 64;
      #pragma unroll
      for (int j = 0; j < 4; ++j)
        __builtin_amdgcn_global_load_lds(
            (const __attribute__((address_space(1))) void*)(ga + (long)j * 8 * KSF),
            (__attribute__((address_space(3))) void*)(la + j * 512), 16, 0, 0);
      f16* lb = &shbuf[BOFF + (wv * 32) * 64];
      #pragma unroll
      for (int j = 0; j < 4; ++j) {
        int brow = wv * 32 + j * 8 + (l >> 3);
        const f16* src = (brow < 64 ? wqp + (long)brow * KSF
                                    : wvp + (long)(brow - 64) * KSF)
                         + (l & 7) * 8 + (long)t * 64;
        __builtin_amdgcn_global_load_lds(
            (const __attribute__((address_space(1))) void*)src,
            (__attribute__((address_space(3))) void*)(lb + j * 512), 16, 0, 0);
      }
    };

    for (int t = 0; t < KT; ++t) {
      stage(t);
      asm volatile("s_waitcnt vmcnt(0)" ::: "memory");
      __syncthreads();
      const f16* base = &shbuf[0];
      f16x8 af[2][2], bf[8][2];
      #pragma unroll
      for (int mi = 0; mi < 2; ++mi)
        #pragma unroll
        for (int kh = 0; kh < 2; ++kh)
          af[mi][kh] = *(const f16x8*)&base[(wv * 32 + mi * 16 + l15) * 64 + (((kh * 4 + lc) ^ lx) << 3)];
      #pragma unroll
      for (int ni = 0; ni < 8; ++ni) {
        int n = ni * 16 + l15;
        #pragma unroll
        for (int kh = 0; kh < 2; ++kh)
          bf[ni][kh] = *(const f16x8*)&base[BOFF + n * 64 + (((kh * 4 + lc) ^ (n & 7)) << 3)];
      }
      #pragma unroll
      for (int mi = 0; mi < 2; ++mi)
        #pragma unroll
        for (int ni = 0; ni < 8; ++ni) {
          acc[mi][ni] = __builtin_amdgcn_mfma_f32_16x16x32_f16(af[mi][0], bf[ni][0], acc[mi][ni], 0, 0, 0);
          acc[mi][ni] = __builtin_amdgcn_mfma_f32_16x16x32_f16(af[mi][1], bf[ni][1], acc[mi][ni], 0, 0, 0);
        }
      __syncthreads();
    }

    f16* st = &shbuf[0];
    #pragma unroll
    for (int ni = 0; ni < 8; ++ni) {
      int col = ni * 16 + l15;
      float bvv = (col < 64) ? bq[col] : bv[col - 64];
      float scl = (col < 64) ? INV_SCALE : 1.f;
      #pragma unroll
      for (int mi = 0; mi < 2; ++mi) {
        int rowl = wv * 32 + mi * 16 + lr;
        #pragma unroll
        for (int r = 0; r < 4; ++r)
          st[(rowl + r) * 128 + col] = (f16)((acc[mi][ni][r] + bvv) * scl);
      }
    }
    __syncthreads();
    f16* oq = Eq16 + (long)z * S * 64;
    f16* ov = Ev16 + (long)z * S * 64;
    for (int c = tid; c < 1024; c += 256) {
      int rw = c >> 3, cc = c & 7;
      *(f16x8*)&oq[(m0 + rw) * 64 + cc * 8] = *(const f16x8*)&st[rw * 128 + cc * 8];
      *(f16x8*)&ov[(m0 + rw) * 64 + cc * 8] = *(const f16x8*)&st[rw * 128 + 64 + cc * 8];
    }
    for (int c = tid; c < 512; c += 256) {
      int lm = c >> 6, d = c & 63;
      float s = 0.f;
      #pragma unroll
      for (int i = 0; i < SEG; ++i) s += (float)st[(lm * SEG + i) * 128 + d];
      float v = s * (1.f / SEG);
      long li = (long)z * NL + (m0 >> 4) + lm;
      qland16[li * 64 + d] = (f16)v;
    }
  } else {
    // ================= Ek / proj body (BM=128) =================
    constexpr int BOFF = 128 * 64;
    int rel = bid - 1024;
    int zz2 = rel >> 4;
    int prob = zz2 >> 3, b = zz2 & 7;
    const f16* Ap = (prob ? Aorig : Aact) + (long)b * S * KSF;
    const f16* Wp = prob ? wp : wk;
    long m0 = (long)(rel & 15) * 128;

    const f16* aW = Ap + (m0 + wv * 32 + (l >> 3)) * KSF + (l & 7) * 8;
    const f16* bW = Wp + ((long)(wv * 16 + (l >> 3))) * KSF + (l & 7) * 8;

    f32x4 acc[2][4];
    #pragma unroll
    for (int i = 0; i < 2; ++i)
      #pragma unroll
      for (int j = 0; j < 4; ++j) acc[i][j] = (f32x4){0.f, 0.f, 0.f, 0.f};

    auto stage = [&](int t) {
      f16* la = &shbuf[(wv * 32) * 64];
      const f16* ga = aW + (long)t * 64;
      #pragma unroll
      for (int j = 0; j < 4; ++j)
        __builtin_amdgcn_global_load_lds(
            (const __attribute__((address_space(1))) void*)(ga + (long)j * 8 * KSF),
            (__attribute__((address_space(3))) void*)(la + j * 512), 16, 0, 0);
      f16* lb = &shbuf[BOFF + (wv * 16) * 64];
      const f16* gb = bW + (long)t * 64;
      #pragma unroll
      for (int j = 0; j < 2; ++j)
        __builtin_amdgcn_global_load_lds(
            (const __attribute__((address_space(1))) void*)(gb + (long)j * 8 * KSF),
            (__attribute__((address_space(3))) void*)(lb + j * 512), 16, 0, 0);
    };

    for (int t = 0; t < KT; ++t) {
      stage(t);
      asm volatile("s_waitcnt vmcnt(0)" ::: "memory");
      __syncthreads();
      const f16* base = &shbuf[0];
      f16x8 af[2][2], bf[4][2];
      #pragma unroll
      for (int mi = 0; mi < 2; ++mi)
        #pragma unroll
        for (int kh = 0; kh < 2; ++kh)
          af[mi][kh] = *(const f16x8*)&base[(wv * 32 + mi * 16 + l15) * 64 + (((kh * 4 + lc) ^ lx) << 3)];
      #pragma unroll
      for (int ni = 0; ni < 4; ++ni)
        #pragma unroll
        for (int kh = 0; kh < 2; ++kh)
          bf[ni][kh] = *(const f16x8*)&base[BOFF + (ni * 16 + l15) * 64 + (((kh * 4 + lc) ^ lx) << 3)];
      #pragma unroll
      for (int mi = 0; mi < 2; ++mi)
        #pragma unroll
        for (int ni = 0; ni < 4; ++ni) {
          acc[mi][ni] = __builtin_amdgcn_mfma_f32_16x16x32_f16(af[mi][0], bf[ni][0], acc[mi][ni], 0, 0, 0);
          acc[mi][ni] = __builtin_amdgcn_mfma_f32_16x16x32_f16(af[mi][1], bf[ni][1], acc[mi][ni], 0, 0, 0);
        }
      __syncthreads();
    }

    if (prob == 0) {
      f16* st = &shbuf[0];
      #pragma unroll
      for (int ni = 0; ni < 4; ++ni) {
        int col = ni * 16 + lcn;
        float bv = bk[col];
        #pragma unroll
        for (int mi = 0; mi < 2; ++mi) {
          int rowl = wv * 32 + mi * 16 + lr;
          #pragma unroll
          for (int r = 0; r < 4; ++r)
            st[(rowl + r) * 64 + col] = (f16)((acc[mi][ni][r] + bv) * INV_SCALE);
        }
      }
      __syncthreads();
      f16* o16 = Ek16 + (long)b * S * 64;
      for (int c = tid; c < 1024; c += 256) {
        int row = c >> 3, cc = c & 7;
        f16x8 v = *(const f16x8*)&st[row * 64 + cc * 8];
        *(f16x8*)&o16[(m0 + row) * 64 + cc * 8] = v;
      }
      for (int c = tid; c < 512; c += 256) {
        int lm = c >> 6, d = c & 63;
        float s = 0.f;
        #pragma unroll
        for (int i = 0; i < SEG; ++i) s += (float)st[(lm * SEG + i) * 64 + d];
        float v = s * (1.f / SEG);
        long li = (long)b * NL + (m0 >> 4) + lm;
        kland16[li * 64 + d] = (f16)v;
      }
    } else {
      float* Cp = projb + (long)b * S * 64;
      #pragma unroll
      for (int ni = 0; ni < 4; ++ni) {
        int col = ni * 16 + lcn;
        float bv = bp[col];
        #pragma unroll
        for (int mi = 0; mi < 2; ++mi) {
          long row = m0 + wv * 32 + mi * 16 + lr;
          #pragma unroll
          for (int r = 0; r < 4; ++r)
            Cp[(row + r) * 64 + col] = (acc[mi][ni][r] + bv) * 0.5f;
        }
      }
    }
  }
}

// ---------------------------------------------------------------- merged kernel_3 | kernel_2
// blocks 0..511: flash (Q frags in regs, K/V staged; 49.7KB -> 3 blocks/CU).
// blocks 512..575: kernel2 MFMA.
__global__ __launch_bounds__(256, 3) void k_land(
    const f16* __restrict__ qland16, const f16* __restrict__ kland16,
    const f16* __restrict__ Ek16, const f16* __restrict__ Ev16,
    const float* __restrict__ aggL, const float* __restrict__ masks,
    float* __restrict__ partU, float* __restrict__ partML,
    f16* __restrict__ k2h, float* __restrict__ colmax)
{
  __shared__ __align__(16) unsigned char smem[49664];
  int bid = blockIdx.x;
  int tid = threadIdx.x;
  int w = tid >> 6, l = tid & 63;
  int l15 = l & 15, lg4 = l >> 4, l7 = l & 7;

  if (bid < 512) {
    // ================= kernel3 body =================
    f16* Ks = (f16*)smem;                    // 128*64 = 16 KB
    f16* Vt = (f16*)(smem + 16384);          // 64*128 = 16 KB
    f16* Pb = (f16*)(smem + 32768);          // 4*16*128 = 16 KB
    float* Ms = (float*)(smem + 49152);      // 128 floats
    int chunk = bid & (NSPL - 1);
    int z2 = bid >> 2;
    int z = z2 >> 1, half = z2 & 1;
    int b = z >> 3, h = z & 7;
    int q0 = half * 64;
    float sigma = fabsf(aggL[h]) + 0.001f;
    float cpos = -sigma * (1.f / 16.f);

    // loop-invariant Q fragments straight from global (R21-proven safe)
    f16x8 af[2];
    #pragma unroll
    for (int kh = 0; kh < 2; ++kh)
      af[kh] = *(const f16x8*)&qland16[((long)z * NL + q0 + w * 16 + l15) * 64 + kh * 32 + lg4 * 8];

    f16* Pw = &Pb[w * 16 * 128];
    f32x4 Oa[4];
    #pragma unroll
    for (int i = 0; i < 4; ++i) Oa[i] = (f32x4){0.f, 0.f, 0.f, 0.f};
    float mrun[4] = {-INFINITY, -INFINITY, -INFINITY, -INFINITY};
    float lrun[4] = {0.f, 0.f, 0.f, 0.f};

    int t0beg = chunk * (S / 128 / NSPL), t0end = t0beg + S / 128 / NSPL;
    for (int t0 = t0beg; t0 < t0end; ++t0) {
      __syncthreads();
      for (int c = tid; c < 1024; c += 256) {
        int k = c >> 3, kc = c & 7;
        f16x8 v = *(const f16x8*)&Ek16[((long)b * S + t0 * 128 + k) * 64 + kc * 8];
        *(f16x8*)&Ks[k * 64 + ((kc ^ (k & 7)) << 3)] = v;
      }
      for (int c = tid; c < 1024; c += 256) {
        int k = c & 127, dc = c >> 7;
        f16x8 v = *(const f16x8*)&Ev16[((long)z * S + t0 * 128 + k) * 64 + dc * 8];
        int kc = k >> 3, ki = k & 7;
        #pragma unroll
        for (int j = 0; j < 8; ++j) {
          int d = dc * 8 + j;
          Vt[d * 128 + ((kc ^ (d & 7)) << 3) + ki] = v[j];
        }
      }
      if (tid < 128)
        Ms[tid] = (masks[(long)b * S + t0 * 128 + tid] == 0.f) ? -1e6f : 0.f;
      __syncthreads();

      f32x4 sc[8];
      #pragma unroll
      for (int ct = 0; ct < 8; ++ct) {
        int n = ct * 16 + l15;
        f16x8 b0 = *(const f16x8*)&Ks[n * 64 + (((lg4) ^ (n & 7)) << 3)];
        f16x8 b1 = *(const f16x8*)&Ks[n * 64 + (((4 + lg4) ^ (n & 7)) << 3)];
        f32x4 zz = (f32x4){0.f, 0.f, 0.f, 0.f};
        zz = __builtin_amdgcn_mfma_f32_16x16x32_f16(af[0], b0, zz, 0, 0, 0);
        sc[ct] = __builtin_amdgcn_mfma_f32_16x16x32_f16(af[1], b1, zz, 0, 0, 0);
      }
      float tmax[4] = {-INFINITY, -INFINITY, -INFINITY, -INFINITY};
      #pragma unroll
      for (int ct = 0; ct < 8; ++ct) {
        float mk = Ms[ct * 16 + l15];
        int key = t0 * 128 + ct * 16 + l15;
        #pragma unroll
        for (int r = 0; r < 4; ++r) {
          int qg = q0 + w * 16 + lg4 * 4 + r;
          float a = (float)(key - 16 * qg);
          float ac = fminf(fmaxf(a, 0.f), 15.f);
          float dd = fabsf(a - ac);
          float sum = ac * ac - 15.f * ac + 120.f + 16.f * dd;
          float s = sc[ct][r] + cpos * sum + mk;
          sc[ct][r] = s;
          tmax[r] = fmaxf(tmax[r], s);
        }
      }
      #pragma unroll
      for (int r = 0; r < 4; ++r) {
        #pragma unroll
        for (int o = 1; o < 16; o <<= 1)
          tmax[r] = fmaxf(tmax[r], __shfl_xor(tmax[r], o));
      }
      float fr[4], lsum[4];
      #pragma unroll
      for (int r = 0; r < 4; ++r) {
        float mnew = fmaxf(mrun[r], tmax[r]);
        fr[r] = expf(mrun[r] - mnew);
        mrun[r] = mnew;
        lsum[r] = 0.f;
      }
      #pragma unroll
      for (int ct = 0; ct < 8; ++ct) {
        #pragma unroll
        for (int r = 0; r < 4; ++r) {
          float p = expf(sc[ct][r] - mrun[r]);
          sc[ct][r] = p;
          lsum[r] += p;
        }
      }
      #pragma unroll
      for (int r = 0; r < 4; ++r) {
        #pragma unroll
        for (int o = 1; o < 16; o <<= 1)
          lsum[r] += __shfl_xor(lsum[r], o);
        lrun[r] = lrun[r] * fr[r] + lsum[r];
      }
      f32x4 fv = (f32x4){fr[0], fr[1], fr[2], fr[3]};
      #pragma unroll
      for (int dt = 0; dt < 4; ++dt) Oa[dt] *= fv;
      #pragma unroll
      for (int ct = 0; ct < 8; ++ct) {
        int kc = ct * 2 + (l15 >> 3);
        int ki = l15 & 7;
        #pragma unroll
        for (int r = 0; r < 4; ++r) {
          int row = lg4 * 4 + r;
          Pw[row * 128 + ((kc ^ (row & 7)) << 3) + ki] = (f16)sc[ct][r];
        }
      }
      #pragma unroll
      for (int ks = 0; ks < 4; ++ks) {
        f16x8 pa = *(const f16x8*)&Pw[l15 * 128 + (((ks * 4 + lg4) ^ l7) << 3)];
        #pragma unroll
        for (int dt = 0; dt < 4; ++dt) {
          int n = dt * 16 + l15;
          f16x8 bv = *(const f16x8*)&Vt[n * 128 + (((ks * 4 + lg4) ^ (n & 7)) << 3)];
          Oa[dt] = __builtin_amdgcn_mfma_f32_16x16x32_f16(pa, bv, Oa[dt], 0, 0, 0);
        }
      }
    }
    #pragma unroll
    for (int r = 0; r < 4; ++r) {
      long qg = q0 + w * 16 + lg4 * 4 + r;
      long base = ((long)z * NL + qg) * NSPL + chunk;
      #pragma unroll
      for (int dt = 0; dt < 4; ++dt)
        partU[base * 64 + dt * 16 + l15] = Oa[dt][r];
      if (l15 == 0) {
        partML[base * 2] = mrun[r];
        partML[base * 2 + 1] = lrun[r];
      }
    }
  } else {
    // ================= kernel2 body (MFMA) =================
    f16* Qs2 = (f16*)smem;                   // 128*64
    f16* Ks2 = (f16*)(smem + 16384);         // 128*64
    float* colpart = (float*)(smem + 32768); // 516 floats
    int z = bid - 512;
    int b2 = z >> 3, h2 = z & 7;
    float sigma = fabsf(aggL[h2]) + 0.001f;
    for (int c = tid; c < 1024; c += 256) {
      int q = c >> 3, kc = c & 7;
      f16x8 v = *(const f16x8*)&qland16[((long)z * NL + q) * 64 + kc * 8];
      *(f16x8*)&Qs2[q * 64 + ((kc ^ (q & 7)) << 3)] = v;
      f16x8 u = *(const f16x8*)&kland16[((long)b2 * NL + q) * 64 + kc * 8];
      *(f16x8*)&Ks2[q * 64 + ((kc ^ (q & 7)) << 3)] = u;
    }
    __syncthreads();
    f32x4 acc[2][8];
    #pragma unroll
    for (int i = 0; i < 2; ++i)
      #pragma unroll
      for (int j = 0; j < 8; ++j) acc[i][j] = (f32x4){0.f, 0.f, 0.f, 0.f};
    f16x8 af[2][2];
    #pragma unroll
    for (int mi = 0; mi < 2; ++mi)
      #pragma unroll
      for (int kh = 0; kh < 2; ++kh)
        af[mi][kh] = *(const f16x8*)&Qs2[(w * 32 + mi * 16 + l15) * 64 + (((kh * 4 + lg4) ^ l7) << 3)];
    #pragma unroll
    for (int ni = 0; ni < 8; ++ni) {
      int n = ni * 16 + l15;
      f16x8 b0 = *(const f16x8*)&Ks2[n * 64 + ((lg4 ^ (n & 7)) << 3)];
      f16x8 b1 = *(const f16x8*)&Ks2[n * 64 + (((4 + lg4) ^ (n & 7)) << 3)];
      #pragma unroll
      for (int mi = 0; mi < 2; ++mi) {
        acc[mi][ni] = __builtin_amdgcn_mfma_f32_16x16x32_f16(af[mi][0], b0, acc[mi][ni], 0, 0, 0);
        acc[mi][ni] = __builtin_amdgcn_mfma_f32_16x16x32_f16(af[mi][1], b1, acc[mi][ni], 0, 0, 0);
      }
    }
    // pos term + row softmax + k2h store + col partials
    float colp[8];
    #pragma unroll
    for (int ni = 0; ni < 8; ++ni) colp[ni] = 0.f;
    f16* o2 = k2h + (long)z * NL * NL;
    #pragma unroll
    for (int mi = 0; mi < 2; ++mi) {
      float tmax[4] = {-INFINITY, -INFINITY, -INFINITY, -INFINITY};
      #pragma unroll
      for (int ni = 0; ni < 8; ++ni) {
        int m = ni * 16 + l15;
        #pragma unroll
        for (int r = 0; r < 4; ++r) {
          int row = w * 32 + mi * 16 + lg4 * 4 + r;
          float dd = fabsf((float)(row - m));
          float s = acc[mi][ni][r] - sigma * ((row == m) ? 5.3125f : 16.f * dd);
          acc[mi][ni][r] = s;
          tmax[r] = fmaxf(tmax[r], s);
        }
      }
      #pragma unroll
      for (int r = 0; r < 4; ++r) {
        #pragma unroll
        for (int o = 1; o < 16; o <<= 1)
          tmax[r] = fmaxf(tmax[r], __shfl_xor(tmax[r], o));
      }
      float lsum2[4] = {0.f, 0.f, 0.f, 0.f};
      #pragma unroll
      for (int ni = 0; ni < 8; ++ni)
        #pragma unroll
        for (int r = 0; r < 4; ++r) {
          float e = expf(acc[mi][ni][r] - tmax[r]);
          acc[mi][ni][r] = e;
          lsum2[r] += e;
        }
      #pragma unroll
      for (int r = 0; r < 4; ++r) {
        #pragma unroll
        for (int o = 1; o < 16; o <<= 1)
          lsum2[r] += __shfl_xor(lsum2[r], o);
        lsum2[r] = 1.f / lsum2[r];
      }
      #pragma unroll
      for (int ni = 0; ni < 8; ++ni) {
        int m = ni * 16 + l15;
        #pragma unroll
        for (int r = 0; r < 4; ++r) {
          float p = acc[mi][ni][r] * lsum2[r];
          o2[(long)(w * 32 + mi * 16 + lg4 * 4 + r) * NL + m] = (f16)p;
          colp[ni] += p;
        }
      }
    }
    #pragma unroll
    for (int ni = 0; ni < 8; ++ni) {
      colp[ni] += __shfl_xor(colp[ni], 16);
      colp[ni] += __shfl_xor(colp[ni], 32);
    }
    if (lg4 == 0) {
      #pragma unroll
      for (int ni = 0; ni < 8; ++ni)
        colpart[w * 128 + ni * 16 + l15] = colp[ni];
    }
    __syncthreads();
    if (tid < 128) {
      float cs = colpart[tid] + colpart[128 + tid] + colpart[256 + tid] + colpart[384 + tid];
      float wm = cs;
      #pragma unroll
      for (int o = 32; o; o >>= 1) wm = fmaxf(wm, __shfl_xor(wm, o));
      if ((tid & 63) == 0) colpart[512 + (tid >> 6)] = wm;
    }
    __syncthreads();
    if (tid == 0) colmax[z] = fmaxf(colpart[512], colpart[513]);
  }
}

// ---------------------------------------------------------------- inverse (MFMA fp16 NS, 8 waves)
__global__ __launch_bounds__(512) void k_inverse(
    const f16* __restrict__ k2h, const float* __restrict__ colmax,
    const float* __restrict__ partU, const float* __restrict__ partML,
    float* __restrict__ m2)
{
  __shared__ __align__(16) f16 bufA[128 * 128];
  __shared__ __align__(16) f16 bufB[128 * 128];
  __shared__ __align__(16) f16 Vt[128 * 128];
  __shared__ __align__(16) f16 Pt[128 * 128];
  int z = blockIdx.x;
  int tid = threadIdx.x;
  int w = tid >> 6, l = tid & 63;
  int l15 = l & 15, lg4 = l >> 4;
  int wr = (w >> 1) * 32, wc = (w & 1) * 64;

  float cv = colmax[l];
  #pragma unroll
  for (int o = 32; o; o >>= 1) cv = fmaxf(cv, __shfl_xor(cv, o));
  float recip = 1.f / cv;

  const f16* key = k2h + (long)z * NL * NL;
  auto swz = [](int r, int c) { return r * 128 + ((((c >> 3) ^ (r & 15))) << 3) + (c & 7); };

  for (int idx = tid; idx < 128 * 16; idx += 512) {
    int r = idx >> 4, c8 = (idx & 15) << 3;
    f16x8 kk = *(const f16x8*)&key[r * 128 + c8];
    f16x8 sv;
    #pragma unroll
    for (int j = 0; j < 8; ++j) sv[j] = (f16)(recip * (float)kk[j]);
    *(f16x8*)&Vt[swz(r, c8)] = sv;
    #pragma unroll
    for (int j = 0; j < 8; ++j) bufA[swz(c8 + j, r)] = sv[j];
  }
  __syncthreads();

  f16* Vc = bufA;
  f16* Sc = bufB;

  f32x4 acc[2][4];
  auto MMc = [&](bool fromGlobal, const f16* Aimg, const f16* Bimg) {
    #pragma unroll
    for (int mi = 0; mi < 2; ++mi)
      #pragma unroll
      for (int ni = 0; ni < 4; ++ni) acc[mi][ni] = (f32x4){0.f, 0.f, 0.f, 0.f};
    #pragma unroll
    for (int ks = 0; ks < 4; ++ks) {
      int k0 = ks * 32 + lg4 * 8;
      f16x8 bf[4];
      #pragma unroll
      for (int ni = 0; ni < 4; ++ni)
        bf[ni] = *(const f16x8*)&Bimg[swz(wc + ni * 16 + l15, k0)];
      f16x8 af[2];
      if (fromGlobal) {
        af[0] = *(const f16x8*)&key[(wr + l15) * 128 + k0];
        af[1] = *(const f16x8*)&key[(wr + 16 + l15) * 128 + k0];
      } else {
        af[0] = *(const f16x8*)&Aimg[swz(wr + l15, k0)];
        af[1] = *(const f16x8*)&Aimg[swz(wr + 16 + l15, k0)];
      }
      #pragma unroll
      for (int mi = 0; mi < 2; ++mi)
        #pragma unroll
        for (int ni = 0; ni < 4; ++ni)
          acc[mi][ni] = __builtin_amdgcn_mfma_f32_16x16x32_f16(af[mi], bf[ni], acc[mi][ni], 0, 0, 0);
    }
  };
  auto store = [&](f16* Nout, f16* Tout, float aT, float bT) {
    #pragma unroll
    for (int mi = 0; mi < 2; ++mi) {
      int row0 = wr + mi * 16 + lg4 * 4;
      #pragma unroll
      for (int ni = 0; ni < 4; ++ni) {
        int col = wc + ni * 16 + l15;
        f16x4 tv;
        #pragma unroll
        for (int r = 0; r < 4; ++r) {
          float v = acc[mi][ni][r];
          if (Nout) Nout[swz(row0 + r, col)] = (f16)v;
          tv[r] = (f16)(aT * v + ((row0 + r == col) ? bT : 0.f));
        }
        *(f16x4*)&Tout[col * 128 + ((((row0 >> 3) ^ (col & 15))) << 3) + (row0 & 7)] = tv;
      }
    }
  };

  for (int it = 0; it < 6; ++it) {
    MMc(true, nullptr, Vt);  store(Sc, Pt, -1.f, 7.f);       __syncthreads();
    MMc(false, Sc, Pt);      store(nullptr, Vt, -1.f, 15.f); __syncthreads();
    MMc(false, Sc, Vt);      store(nullptr, Pt, -0.25f, 3.25f); __syncthreads();
    MMc(false, Vc, Pt);      store(Sc, Vt, 1.f, 0.f);        __syncthreads();
    f16* tsw = Vc; Vc = Sc; Sc = tsw;
  }

  for (int idx = tid; idx < 128 * 16; idx += 512) {
    int q = idx >> 4, c4 = (idx & 15) << 2;
    long base = ((long)z * NL + q) * NSPL;
    float m[NSPL], lv[NSPL];
    #pragma unroll
    for (int c = 0; c < NSPL; ++c) {
      m[c] = partML[(base + c) * 2];
      lv[c] = partML[(base + c) * 2 + 1];
    }
    float M = fmaxf(fmaxf(m[0], m[1]), fmaxf(m[2], m[3]));
    float L = 0.f, scf[NSPL];
    #pragma unroll
    for (int c = 0; c < NSPL; ++c) {
      scf[c] = expf(m[c] - M);
      L += lv[c] * scf[c];
    }
    float4 o = make_float4(0.f, 0.f, 0.f, 0.f);
    #pragma unroll
    for (int c = 0; c < NSPL; ++c) {
      float4 u = *(const float4*)&partU[(base + c) * 64 + c4];
      o.x += scf[c] * u.x; o.y += scf[c] * u.y;
      o.z += scf[c] * u.z; o.w += scf[c] * u.w;
    }
    float invL = 1.f / L;
    Pt[swz(c4 + 0, q)] = (f16)(o.x * invL);
    Pt[swz(c4 + 1, q)] = (f16)(o.y * invL);
    Pt[swz(c4 + 2, q)] = (f16)(o.z * invL);
    Pt[swz(c4 + 3, q)] = (f16)(o.w * invL);
  }
  __syncthreads();
  f32x4 accF[4];
  #pragma unroll
  for (int ni = 0; ni < 4; ++ni) accF[ni] = (f32x4){0.f, 0.f, 0.f, 0.f};
  #pragma unroll
  for (int ks = 0; ks < 4; ++ks) {
    int k0 = ks * 32 + lg4 * 8;
    f16x8 af = *(const f16x8*)&Vc[swz(w * 16 + l15, k0)];
    #pragma unroll
    for (int ni = 0; ni < 4; ++ni) {
      f16x8 bf = *(const f16x8*)&Pt[swz(ni * 16 + l15, k0)];
      accF[ni] = __builtin_amdgcn_mfma_f32_16x16x32_f16(af, bf, accF[ni], 0, 0, 0);
    }
  }
  float* mp = m2 + (long)z * NL * VF;
  #pragma unroll
  for (int ni = 0; ni < 4; ++ni)
    #pragma unroll
    for (int r = 0; r < 4; ++r)
      mp[(long)(w * 16 + lg4 * 4 + r) * VF + ni * 16 + l15] = accF[ni][r];
}

// ---------------------------------------------------------------- kernel_1 + attn + merge (MFMA)
__global__ __launch_bounds__(256, 2) void k_k1attn(
    const f16* __restrict__ Eq16, const f16* __restrict__ kland16,
    const float* __restrict__ aggL, const float* __restrict__ m2,
    const float* __restrict__ proj, f16* __restrict__ merged)
{
  __shared__ __align__(16) f16 Kl[128 * 64];
  __shared__ __align__(16) f16 M2t[64 * 128];
  __shared__ __align__(16) f16 Pb[4 * 16 * 128];
  int zz = blockIdx.x;
  int z = zz >> 5, st = zz & 31;
  int b = z >> 3, h = z & 7;
  int s0 = st * 64;
  int tid = threadIdx.x;
  int w = tid >> 6, l = tid & 63;
  int l15 = l & 15, lg4 = l >> 4, l7 = l & 7;
  float sigma = fabsf(aggL[h]) + 0.001f;
  float cpos = -sigma * (1.f / 16.f);

  for (int c = tid; c < 128 * 8; c += 256) {
    int k = c >> 3, kc = c & 7;
    f16x8 v = *(const f16x8*)&kland16[((long)b * NL + k) * 64 + kc * 8];
    *(f16x8*)&Kl[k * 64 + ((kc ^ (k & 7)) << 3)] = v;
  }
  const float* mp = m2 + (long)z * NL * VF;
  for (int c = tid; c < 128 * 16; c += 256) {
    int k = c >> 4, c4 = (c & 15) << 2;
    float4 v4 = *(const float4*)&mp[k * 64 + c4];
    int kc = k >> 3, ki = k & 7;
    M2t[(c4 + 0) * 128 + ((kc ^ ((c4 + 0) & 7)) << 3) + ki] = (f16)v4.x;
    M2t[(c4 + 1) * 128 + ((kc ^ ((c4 + 1) & 7)) << 3) + ki] = (f16)v4.y;
    M2t[(c4 + 2) * 128 + ((kc ^ ((c4 + 2) & 7)) << 3) + ki] = (f16)v4.z;
    M2t[(c4 + 3) * 128 + ((kc ^ ((c4 + 3) & 7)) << 3) + ki] = (f16)v4.w;
  }
  __syncthreads();

  long qrow = (long)z * S + s0 + w * 16 + l15;
  f16x8 af[2];
  #pragma unroll
  for (int kh = 0; kh < 2; ++kh)
    af[kh] = *(const f16x8*)&Eq16[qrow * 64 + kh * 32 + lg4 * 8];

  f32x4 sc[8];
  #pragma unroll
  for (int ct = 0; ct < 8; ++ct) {
    int n = ct * 16 + l15;
    f16x8 b0 = *(const f16x8*)&Kl[n * 64 + ((lg4 ^ (n & 7)) << 3)];
    f16x8 b1 = *(const f16x8*)&Kl[n * 64 + (((4 + lg4) ^ (n & 7)) << 3)];
    f32x4 zz4 = (f32x4){0.f, 0.f, 0.f, 0.f};
    zz4 = __builtin_amdgcn_mfma_f32_16x16x32_f16(af[0], b0, zz4, 0, 0, 0);
    sc[ct] = __builtin_amdgcn_mfma_f32_16x16x32_f16(af[1], b1, zz4, 0, 0, 0);
  }
  float tmax[4] = {-INFINITY, -INFINITY, -INFINITY, -INFINITY};
  #pragma unroll
  for (int ct = 0; ct < 8; ++ct) {
    int lm = ct * 16 + l15;
    #pragma unroll
    for (int r = 0; r < 4; ++r) {
      int spos = s0 + w * 16 + lg4 * 4 + r;
      float a = (float)(spos - 16 * lm);
      float ac = fminf(fmaxf(a, 0.f), 15.f);
      float dd = fabsf(a - ac);
      float sum = ac * ac - 15.f * ac + 120.f + 16.f * dd;
      float s = sc[ct][r] + cpos * sum;
      sc[ct][r] = s;
      tmax[r] = fmaxf(tmax[r], s);
    }
  }
  #pragma unroll
  for (int r = 0; r < 4; ++r) {
    #pragma unroll
    for (int o = 1; o < 16; o <<= 1)
      tmax[r] = fmaxf(tmax[r], __shfl_xor(tmax[r], o));
  }
  float lsum[4] = {0.f, 0.f, 0.f, 0.f};
  #pragma unroll
  for (int ct = 0; ct < 8; ++ct) {
    #pragma unroll
    for (int r = 0; r < 4; ++r) {
      float p = expf(sc[ct][r] - tmax[r]);
      sc[ct][r] = p;
      lsum[r] += p;
    }
  }
  #pragma unroll
  for (int r = 0; r < 4; ++r) {
    #pragma unroll
    for (int o = 1; o < 16; o <<= 1)
      lsum[r] += __shfl_xor(lsum[r], o);
    lsum[r] = 1.f / lsum[r];
  }
  f16* Pw = &Pb[w * 16 * 128];
  #pragma unroll
  for (int ct = 0; ct < 8; ++ct) {
    int kc = ct * 2 + (l15 >> 3);
    int ki = l15 & 7;
    #pragma unroll
    for (int r = 0; r < 4; ++r) {
      int row = lg4 * 4 + r;
      Pw[row * 128 + ((kc ^ (row & 7)) << 3) + ki] = (f16)(sc[ct][r] * lsum[r]);
    }
  }
  f32x4 Oa[4];
  #pragma unroll
  for (int i = 0; i < 4; ++i) Oa[i] = (f32x4){0.f, 0.f, 0.f, 0.f};
  #pragma unroll
  for (int ks = 0; ks < 4; ++ks) {
    f16x8 pa = *(const f16x8*)&Pw[l15 * 128 + (((ks * 4 + lg4) ^ l7) << 3)];
    #pragma unroll
    for (int dt = 0; dt < 4; ++dt) {
      int n = dt * 16 + l15;
      f16x8 bv = *(const f16x8*)&M2t[n * 128 + (((ks * 4 + lg4) ^ (n & 7)) << 3)];
      Oa[dt] = __builtin_amdgcn_mfma_f32_16x16x32_f16(pa, bv, Oa[dt], 0, 0, 0);
    }
  }
  #pragma unroll
  for (int r = 0; r < 4; ++r) {
    long srow = (long)b * S + s0 + w * 16 + lg4 * 4 + r;
    int r7 = (int)(srow & 7);
    #pragma unroll
    for (int dt = 0; dt < 4; ++dt) {
      int col = dt * 16 + l15;
      float v = Oa[dt][r] + proj[srow * VF + col];
      merged[srow * (long)HV + h * 64 + (((col >> 3) ^ r7) << 3) + (col & 7)] = (f16)v;
    }
  }
}

} // namespace

extern "C" void kernel_launch(void* const* d_in, const int* in_sizes, int n_in,
                              void* d_out, int out_size, void* d_ws, size_t ws_size,
                              hipStream_t stream)
{
  const float* lat   = (const float*)d_in[0];
  const float* masks = (const float*)d_in[1];
  const float* xemb  = (const float*)d_in[2];
  const float* ccls  = (const float*)d_in[4];
  const float* qlin  = (const float*)d_in[5];
  const float* klin  = (const float*)d_in[6];
  const float* vlin  = (const float*)d_in[7];
  const float* plin  = (const float*)d_in[8];
  const float* agg   = (const float*)d_in[9];
  const float* cfeat = (const float*)d_in[10];
  float* out = (float*)d_out;
  float* ws = (float*)d_ws;

  long off = 0;
  auto allocF = [&](long n) { float* p = ws + off; off += (n + 3) & ~3L; return p; };
  auto allocH = [&](long n) { f16* p = (f16*)(ws + off); off += ((n + 1) / 2 + 3) & ~3L; return p; };

  f16* origA = allocH(ROWS * KSF);
  f16* vbufA = allocH(ROWS * KSF);
  f16* merged = allocH(ROWS * (long)HV);
  f16* WQt = allocH(16L * 64 * KSF);
  f16* WKt = allocH(2L * 64 * KSF);
  f16* WVt = allocH(16L * 64 * KSF);
  f16* WPt = allocH(2L * 64 * KSF);
  f16* WCFt = allocH((long)KSF * 512);
  f16* WCCt = allocH(64L * 512);
  f16* Ek16 = allocH((long)B * S * 64);
  f16* Ev16 = allocH((long)B * H * S * 64);
  f16* Eq16 = allocH((long)B * H * S * 64);
  f16* qland16 = allocH((long)B * H * NL * DF);
  f16* kland16 = allocH((long)B * NL * DF);
  f16* k2h = allocH((long)B * H * NL * NL);
  float* cl     = allocF(ROWS * HS);
  float* projb  = allocF((long)B * S * VF);
  float* m2b    = allocF((long)B * H * NL * VF);
  float* colmax = allocF(64);
  float* partU  = allocF((long)B * H * NL * NSPL * 64);
  float* partML = allocF((long)B * H * NL * NSPL * 2);

  k_cl<<<(int)(ROWS / 4), 256, 0, stream>>>(lat, masks, cl);
  k_prep<<<10752 + 1864, 256, 0, stream>>>(xemb, cl, qlin, klin, vlin, plin,
      cfeat, ccls, origA, WQt, WKt, WVt, WPt, WCFt, WCCt);

  const f16* Aact = origA;
  for (int layer = 0; layer < 2; ++layer) {
    const f16* wq = WQt + (long)layer * 8 * 64 * KSF;
    const f16* wk = WKt + (long)layer * 64 * KSF;
    const f16* wvv = WVt + (long)layer * 8 * 64 * KSF;
    const f16* wp = WPt + (long)layer * 64 * KSF;
    const float* bq = qlin + (long)layer * 8 * FEATP * 64 + (long)(FEATP - 2) * 64;
    const float* bk = klin + (long)layer * FEATP * 64 + (long)(FEATP - 2) * 64;
    const float* bv = vlin + (long)layer * 8 * FEATP * 64 + (long)(FEATP - 2) * 64;
    const float* bp = plin + (long)layer * FEATP * 64 + (long)(FEATP - 2) * 64;
    const float* ag = agg + layer * H;

    k_qve<<<1280, 256, 0, stream>>>(Aact, origA, wq, wvv, wk, wp,
        bq, bv, bk, bp, Eq16, Ev16, Ek16, projb, qland16, kland16);

    k_land<<<576, 256, 0, stream>>>(qland16, kland16, Ek16, Ev16, ag, masks,
        partU, partML, k2h, colmax);
    k_inverse<<<B * H, 512, 0, stream>>>(k2h, colmax, partU, partML, m2b);
    k_k1attn<<<B * H * (S / 64), 256, 0, stream>>>(Eq16, kland16, ag, m2b, projb, merged);

    if (layer == 0) {
      dim3 gC(64, 21, 1);
      k_mgemm<<<gC, 256, 0, stream>>>(merged, 0, 1, WCFt, 0, 1, 8, 1,
          nullptr, 0, 0, nullptr, 0, 1.0f, vbufA, FEAT, nullptr);
      Aact = vbufA;
    } else {
      dim3 gO(64, 1, 1);
      k_mgemm<<<gO, 256, 0, stream>>>(merged, 0, 1, WCCt, 0, 1, 8, 2,
          out, 0, HS, nullptr, 0, 1.0f, nullptr, HS, masks);
    }
  }
  (void)in_sizes; (void)n_in; (void)out_size; (void)ws_size;
}